// Round 2
// baseline (143.991 us; speedup 1.0000x reference)
//
#include <hip/hip_runtime.h>
#include <math.h>

#define B_  16
#define C_  256
#define S_  1024
#define NH  4
#define DK  64
#define P3  768   // 3*NH*DK
#define ND  256   // NH*DK

typedef unsigned short u16;
typedef unsigned int   u32;
typedef float  f32x4  __attribute__((ext_vector_type(4)));
typedef short  bf16x8 __attribute__((ext_vector_type(8)));

#define MFMA16(a, b, c) __builtin_amdgcn_mfma_f32_16x16x32_bf16(a, b, c, 0, 0, 0)

// fold softmax scale*log2(e) into q at projection time
#define QSCALE 0.1803368801111137f   // 0.125 * 1.44269504

// counted waitcnt + raw barrier (no vmcnt(0) drain — the __syncthreads killer)
#define WAITVM(N) asm volatile("s_waitcnt vmcnt(" #N ")" ::: "memory")
#define BARRIER() asm volatile("s_barrier" ::: "memory")

__device__ __forceinline__ u16 f2bf(float f) {
    union { float f; u32 u; } x; x.f = f;
    u32 r = x.u + 0x7fffu + ((x.u >> 16) & 1u);   // RNE
    return (u16)(r >> 16);
}

// packed f32 pair -> 2x bf16 in one VALU op (RNE)
__device__ __forceinline__ u32 cvtpk(float lo, float hi) {
    u32 r;
    asm("v_cvt_pk_bf16_f32 %0, %1, %2" : "=v"(r) : "v"(lo), "v"(hi));
    return r;
}

// async global->LDS, 16B per lane; LDS dest is wave-uniform base + lane*16
__device__ __forceinline__ void stage16(const u16* g, u16* l) {
    __builtin_amdgcn_global_load_lds(
        (const __attribute__((address_space(1))) void*)g,
        (__attribute__((address_space(3))) void*)l, 16, 0, 0);
}

// ---------------------------------------------------------------------------
// All transposes in ONE launch:
//   z in [0,16): x slice z: [256][1024] -> xt [1024][256] (fp32->bf16)
//   z == 16:     w_proj [256][768] -> wpT [768][256]
//   z == 17:     w_out  [256][256] -> woT [256][256]
// ---------------------------------------------------------------------------
__global__ __launch_bounds__(256) void transpose_all(
    const float* __restrict__ x, u16* __restrict__ xt,
    const float* __restrict__ wp, u16* __restrict__ wpT,
    const float* __restrict__ wo, u16* __restrict__ woT)
{
    const int z = blockIdx.z;
    const float* src;
    u16* dst;
    int Cc;
    if (z < 16)       { src = x + (size_t)z * C_ * S_; dst = xt + (size_t)z * C_ * S_; Cc = S_; }
    else if (z == 16) { src = wp; dst = wpT; Cc = P3; }
    else              { src = wo; dst = woT; Cc = ND; }
    if ((int)blockIdx.x * 64 >= Cc) return;
    const int R = C_;   // 256 rows for all three

    __shared__ float T[64][65];
    const int tid = threadIdx.x;
    const int c0 = blockIdx.x * 64, r0 = blockIdx.y * 64;

    const int l64 = tid & 63, rr0 = tid >> 6;
    #pragma unroll
    for (int t = 0; t < 16; ++t) {
        int rr = rr0 + t * 4;
        T[rr][l64] = src[(size_t)(r0 + rr) * Cc + c0 + l64];
    }
    __syncthreads();
    const int rp = tid & 31;
    const int cb = tid >> 5;
    #pragma unroll
    for (int t = 0; t < 8; ++t) {
        int c = cb + t * 8;
        u32 lo = f2bf(T[2 * rp][c]);
        u32 hi = f2bf(T[2 * rp + 1][c]);
        *(u32*)&dst[(size_t)(c0 + c) * R + r0 + 2 * rp] = lo | (hi << 16);
    }
}

// ---------------------------------------------------------------------------
// QKV projection: 128(M=s) x 64(N=n) tile, 4 waves x (32x64).
// BK=64, 4 phases, double-buffered LDS prefetch (counted vmcnt, raw barriers).
// q gets QSCALE folded in. v stored TRANSPOSED [bh][dk][s].
// ---------------------------------------------------------------------------
__global__ __launch_bounds__(256) void qkv_mfma(
    const u16* __restrict__ xt, const u16* __restrict__ wpT,
    const float* __restrict__ bp, u16* __restrict__ qo,
    u16* __restrict__ ko, u16* __restrict__ vo)
{
    // 2 x (As 8192 [128 rows x 64 k] + Bs 4096 [64 rows x 64 k]) = 48 KB
    __shared__ __align__(16) u16 SM[24576];

    const int tid = threadIdx.x;
    const int w = tid >> 6, lane = tid & 63;
    const int n_ = lane & 15, quad = lane >> 4;
    const int n0 = blockIdx.x * 64, s0 = blockIdx.y * 128, b = blockIdx.z;

    const u16* ar0 = xt + ((size_t)b * S_ + s0 + (2 * w + 0) * 16 + n_) * C_ + quad * 8;
    const u16* ar1 = xt + ((size_t)b * S_ + s0 + (2 * w + 1) * 16 + n_) * C_ + quad * 8;
    const u16* br  = wpT + (size_t)(n0 + w * 16 + n_) * C_ + quad * 8;

    f32x4 acc[2][4];
    #pragma unroll
    for (int am = 0; am < 2; ++am)
        #pragma unroll
        for (int nf = 0; nf < 4; ++nf)
            #pragma unroll
            for (int r = 0; r < 4; ++r) acc[am][nf][r] = 0.f;

    // prologue: stage phase 0 into buf 0 (6 loads/wave)
    {
        u16* As_ = SM;
        u16* Bs_ = SM + 8192;
        stage16(ar0,      As_ + (4 * w + 0) * 512);
        stage16(ar0 + 32, As_ + (4 * w + 1) * 512);
        stage16(ar1,      As_ + (4 * w + 2) * 512);
        stage16(ar1 + 32, As_ + (4 * w + 3) * 512);
        stage16(br,       Bs_ + (2 * w + 0) * 512);
        stage16(br + 32,  Bs_ + (2 * w + 1) * 512);
    }

    #pragma unroll
    for (int p = 0; p < 4; ++p) {
        u16* As_ = SM + (p & 1) * 12288;
        u16* Bs_ = As_ + 8192;
        if (p < 3) {
            const int pk = (p + 1) * 64;
            u16* An = SM + ((p + 1) & 1) * 12288;
            u16* Bn = An + 8192;
            stage16(ar0 + pk,      An + (4 * w + 0) * 512);
            stage16(ar0 + pk + 32, An + (4 * w + 1) * 512);
            stage16(ar1 + pk,      An + (4 * w + 2) * 512);
            stage16(ar1 + pk + 32, An + (4 * w + 3) * 512);
            stage16(br  + pk,      Bn + (2 * w + 0) * 512);
            stage16(br  + pk + 32, Bn + (2 * w + 1) * 512);
            WAITVM(6);   // phase-p loads done; p+1's 6 stay in flight
        } else {
            WAITVM(0);
        }
        BARRIER();
        #pragma unroll
        for (int kc = 0; kc < 2; ++kc) {
            bf16x8 af0 = *(const bf16x8*)&As_[((2 * w + 0) * 2 + kc) * 512 + lane * 8];
            bf16x8 af1 = *(const bf16x8*)&As_[((2 * w + 1) * 2 + kc) * 512 + lane * 8];
            #pragma unroll
            for (int nf = 0; nf < 4; ++nf) {
                bf16x8 bf = *(const bf16x8*)&Bs_[(nf * 2 + kc) * 512 + lane * 8];
                acc[0][nf] = MFMA16(af0, bf, acc[0][nf]);
                acc[1][nf] = MFMA16(af1, bf, acc[1][nf]);
            }
        }
        if (p < 3) BARRIER();   // all waves done reading buf before restage
    }

    const int hd = n0 / 192, rem = n0 % 192, which = rem / 64;
    const int bh = b * NH + hd;
    float bias[4];
    #pragma unroll
    for (int nf = 0; nf < 4; ++nf) bias[nf] = bp[n0 + nf * 16 + n_];
    const float sc = (which == 0) ? QSCALE : 1.f;

    __syncthreads();   // full drain once; reuse SM for epilogue
    if (which < 2) {
        u16* Cs = SM;                      // [128][72]
        #pragma unroll
        for (int am = 0; am < 2; ++am) {
            int row0 = w * 32 + am * 16 + quad * 4;
            #pragma unroll
            for (int nf = 0; nf < 4; ++nf)
                #pragma unroll
                for (int r = 0; r < 4; ++r)
                    Cs[(row0 + r) * 72 + nf * 16 + n_] =
                        f2bf((acc[am][nf][r] + bias[nf]) * sc);
        }
        __syncthreads();
        u16* dst = (which == 0) ? qo : ko;
        #pragma unroll
        for (int t = 0; t < 4; ++t) {
            int ii = tid + t * 256;
            int row = ii >> 3, c8 = (ii & 7) * 8;
            *(bf16x8*)&dst[((size_t)bh * S_ + s0 + row) * DK + c8] =
                *(const bf16x8*)&Cs[row * 72 + c8];
        }
    } else {
        u16* Cs = SM;                      // [64][136] (dk-major, plain s cols)
        #pragma unroll
        for (int am = 0; am < 2; ++am) {
            int colb = w * 32 + am * 16 + quad * 4;
            #pragma unroll
            for (int nf = 0; nf < 4; ++nf)
                #pragma unroll
                for (int r = 0; r < 4; ++r)
                    Cs[(nf * 16 + n_) * 136 + colb + r] =
                        f2bf(acc[am][nf][r] + bias[nf]);
        }
        __syncthreads();
        #pragma unroll
        for (int t = 0; t < 4; ++t) {
            int ii = tid + t * 256;
            int row = ii >> 4, c8 = (ii & 15) * 8;
            *(bf16x8*)&vo[((size_t)bh * DK + row) * S_ + s0 + c8] =
                *(const bf16x8*)&Cs[row * 136 + c8];
        }
    }
}

// ---------------------------------------------------------------------------
// Flash attention: block = 64 q (4 waves x 16 q), 64-key tiles, no-max
// softmax. S computed TRANSPOSED (A=K with kappa-permuted rows, B=Q) so the
// P^T C-layout -> PV B-operand transform is a pure register repack.
// Grid = 1024 one-dim blocks with XCD-bijective swizzle: each XCD's
// 128-block chunk covers 8 complete (b,head) groups -> K/V L2-resident.
// Double-buffered K/V staging, counted vmcnt, raw barriers, setprio on MFMA.
// ---------------------------------------------------------------------------
__global__ __launch_bounds__(256) void attn_mfma(
    const u16* __restrict__ q, const u16* __restrict__ k,
    const u16* __restrict__ vt, u16* __restrict__ obf)
{
    // 2 x (Ks 4096 + Vs 4096) = 32 KB; epilogue reuses first 4608 u16
    __shared__ __align__(16) u16 SM[16384];

    const int tid = threadIdx.x;
    const int w = tid >> 6, lane = tid & 63;
    const int n_ = lane & 15, quad = lane >> 4;

    // XCD swizzle (8 XCDs, 1024 blocks, 128-block chunks)
    const int id  = blockIdx.x;
    const int nid = (id & 7) * 128 + (id >> 3);
    const int i0  = (nid & 15) * 64;
    const int hd  = (nid >> 4) & 3;
    const int b   = nid >> 6;
    const int bh  = b * NH + hd;

    // Q fragments (B-operand; scale pre-folded): query = i0 + w*16 + n_
    bf16x8 qf[2];
    {
        const u16* qrow = q + ((size_t)bh * S_ + i0 + w * 16 + n_) * DK;
        qf[0] = *(const bf16x8*)&qrow[quad * 8];
        qf[1] = *(const bf16x8*)&qrow[32 + quad * 8];
    }

    // K staging with kappa row permutation (staging wave w = MFMA block nb)
    const int kappa = 32 * (w & 1) + 8 * (n_ >> 2) + 4 * (w >> 1) + (n_ & 3);
    const u16* kbase = k  + ((size_t)bh * S_ + kappa) * DK + quad * 8;
    const u16* vbase = vt + ((size_t)bh * DK + w * 16 + n_) * S_ + quad * 8;

    float lsum = 0.f;
    f32x4 oacc[4];
    #pragma unroll
    for (int nd = 0; nd < 4; ++nd)
        #pragma unroll
        for (int r = 0; r < 4; ++r) oacc[nd][r] = 0.f;

    // prologue: stage tile 0 into buf 0 (4 loads/wave)
    stage16(kbase,      SM + w * 1024);
    stage16(kbase + 32, SM + w * 1024 + 512);
    stage16(vbase,      SM + 4096 + w * 1024);
    stage16(vbase + 32, SM + 4096 + w * 1024 + 512);

    for (int t = 0; t < 16; ++t) {
        u16* Ks = SM + (t & 1) * 8192;
        u16* Vs = Ks + 4096;
        if (t < 15) {
            const size_t jn = (size_t)(t + 1) * 64;
            u16* Kn = SM + ((t + 1) & 1) * 8192;
            u16* Vn = Kn + 4096;
            stage16(kbase + jn * DK,      Kn + w * 1024);
            stage16(kbase + jn * DK + 32, Kn + w * 1024 + 512);
            stage16(vbase + jn,           Vn + w * 1024);
            stage16(vbase + jn + 32,      Vn + w * 1024 + 512);
            WAITVM(4);   // tile-t loads landed; t+1's 4 stay in flight
        } else {
            WAITVM(0);
        }
        BARRIER();

        // S^T = K Q^T : C rows = permuted keys, cols = queries (n_)
        f32x4 sb[4];
        __builtin_amdgcn_s_setprio(1);
        #pragma unroll
        for (int nb = 0; nb < 4; ++nb) {
            bf16x8 kf0 = *(const bf16x8*)&Ks[nb * 1024 + lane * 8];
            bf16x8 kf1 = *(const bf16x8*)&Ks[nb * 1024 + 512 + lane * 8];
            f32x4 a; a[0] = a[1] = a[2] = a[3] = 0.f;
            a = MFMA16(kf0, qf[0], a);
            a = MFMA16(kf1, qf[1], a);
            sb[nb] = a;
        }
        __builtin_amdgcn_s_setprio(0);

        // exp2 (f32), sum, packed-convert into PV B-operand layout
        float pr[4][4];
        #pragma unroll
        for (int nb = 0; nb < 4; ++nb)
            #pragma unroll
            for (int r = 0; r < 4; ++r) {
                float p = exp2f(sb[nb][r]);
                lsum += p;
                pr[nb][r] = p;
            }
        bf16x8 pa[2];
        {
            union { bf16x8 v; u32 u[4]; } p0, p1;
            p0.u[0] = cvtpk(pr[0][0], pr[0][1]);
            p0.u[1] = cvtpk(pr[0][2], pr[0][3]);
            p0.u[2] = cvtpk(pr[2][0], pr[2][1]);
            p0.u[3] = cvtpk(pr[2][2], pr[2][3]);
            p1.u[0] = cvtpk(pr[1][0], pr[1][1]);
            p1.u[1] = cvtpk(pr[1][2], pr[1][3]);
            p1.u[2] = cvtpk(pr[3][0], pr[3][1]);
            p1.u[3] = cvtpk(pr[3][2], pr[3][3]);
            pa[0] = p0.v;
            pa[1] = p1.v;
        }

        // O^T += V^T P^T : A = V^T frags (key-slots identity), B = pa
        __builtin_amdgcn_s_setprio(1);
        #pragma unroll
        for (int nd = 0; nd < 4; ++nd) {
            bf16x8 vf0 = *(const bf16x8*)&Vs[nd * 1024 + lane * 8];
            bf16x8 vf1 = *(const bf16x8*)&Vs[nd * 1024 + 512 + lane * 8];
            oacc[nd] = MFMA16(vf0, pa[0], oacc[nd]);
            oacc[nd] = MFMA16(vf1, pa[1], oacc[nd]);
        }
        __builtin_amdgcn_s_setprio(0);

        if (t < 15) BARRIER();   // all waves done reading buf before restage
    }

    // total = sum over 4 quads (all 16 in-lane values are for query n_)
    float s = lsum;
    s += __shfl_xor(s, 16);
    s += __shfl_xor(s, 32);
    const float inv = 1.f / s;

    // epilogue: O^T[dk=nd*16+quad*4+r][query=n_] -> eb[query-local][dk]
    __syncthreads();   // full drain once; reuse SM
    u16* eb = SM + w * 1152;   // [16][72]
    #pragma unroll
    for (int nd = 0; nd < 4; ++nd) {
        uint2 uv;
        uv.x = cvtpk(oacc[nd][0] * inv, oacc[nd][1] * inv);
        uv.y = cvtpk(oacc[nd][2] * inv, oacc[nd][3] * inv);
        *(uint2*)&eb[n_ * 72 + nd * 16 + quad * 4] = uv;
    }
    __syncthreads();
    #pragma unroll
    for (int t = 0; t < 2; ++t) {
        int ii = lane + t * 64;
        int row = ii >> 3, c8 = (ii & 7) * 8;
        *(bf16x8*)&obf[((size_t)b * S_ + i0 + w * 16 + row) * ND + hd * DK + c8] =
            *(const bf16x8*)&eb[row * 72 + c8];
    }
}

// ---------------------------------------------------------------------------
// Out projection: A = woT (M=c=64), B = obf (N=s=128).
// BK=64, 4 phases, double-buffered prefetch like qkv.
// C[c][s] layout -> direct coalesced stores out[b][c][s] (+bias+residual).
// ---------------------------------------------------------------------------
__global__ __launch_bounds__(256) void out_proj_mfma(
    const u16* __restrict__ obf, const u16* __restrict__ woT,
    const float* __restrict__ bo, const float* __restrict__ x,
    float* __restrict__ out)
{
    // 2 x (Bs 8192 [128 rows x 64 k] + As 4096 [64 rows x 64 k]) = 48 KB
    __shared__ __align__(16) u16 SM[24576];

    const int tid = threadIdx.x;
    const int w = tid >> 6, lane = tid & 63;
    const int n_ = lane & 15, quad = lane >> 4;
    const int c0 = blockIdx.x * 64, s0 = blockIdx.y * 128, b = blockIdx.z;

    const u16* ar  = woT + (size_t)(c0 + w * 16 + n_) * ND + quad * 8;
    const u16* br0 = obf + ((size_t)b * S_ + s0 + (2 * w + 0) * 16 + n_) * ND + quad * 8;
    const u16* br1 = obf + ((size_t)b * S_ + s0 + (2 * w + 1) * 16 + n_) * ND + quad * 8;

    f32x4 acc[2][4];
    #pragma unroll
    for (int nf = 0; nf < 2; ++nf)
        #pragma unroll
        for (int mb = 0; mb < 4; ++mb)
            #pragma unroll
            for (int r = 0; r < 4; ++r) acc[nf][mb][r] = 0.f;

    // prologue: stage phase 0 into buf 0
    {
        u16* Bs_ = SM;
        u16* As_ = SM + 8192;
        stage16(br0,      Bs_ + (4 * w + 0) * 512);
        stage16(br0 + 32, Bs_ + (4 * w + 1) * 512);
        stage16(br1,      Bs_ + (4 * w + 2) * 512);
        stage16(br1 + 32, Bs_ + (4 * w + 3) * 512);
        stage16(ar,       As_ + (2 * w + 0) * 512);
        stage16(ar + 32,  As_ + (2 * w + 1) * 512);
    }

    #pragma unroll
    for (int p = 0; p < 4; ++p) {
        u16* Bs_ = SM + (p & 1) * 12288;
        u16* As_ = Bs_ + 8192;
        if (p < 3) {
            const int pk = (p + 1) * 64;
            u16* Bn = SM + ((p + 1) & 1) * 12288;
            u16* An = Bn + 8192;
            stage16(br0 + pk,      Bn + (4 * w + 0) * 512);
            stage16(br0 + pk + 32, Bn + (4 * w + 1) * 512);
            stage16(br1 + pk,      Bn + (4 * w + 2) * 512);
            stage16(br1 + pk + 32, Bn + (4 * w + 3) * 512);
            stage16(ar  + pk,      An + (2 * w + 0) * 512);
            stage16(ar  + pk + 32, An + (2 * w + 1) * 512);
            WAITVM(6);
        } else {
            WAITVM(0);
        }
        BARRIER();
        #pragma unroll
        for (int kc = 0; kc < 2; ++kc) {
            bf16x8 bf0 = *(const bf16x8*)&Bs_[((2 * w + 0) * 2 + kc) * 512 + lane * 8];
            bf16x8 bf1 = *(const bf16x8*)&Bs_[((2 * w + 1) * 2 + kc) * 512 + lane * 8];
            #pragma unroll
            for (int mb = 0; mb < 4; ++mb) {
                bf16x8 af = *(const bf16x8*)&As_[(mb * 2 + kc) * 512 + lane * 8];
                acc[0][mb] = MFMA16(af, bf0, acc[0][mb]);
                acc[1][mb] = MFMA16(af, bf1, acc[1][mb]);
            }
        }
        if (p < 3) BARRIER();
    }

    // direct epilogue: c = c0+mb*16+quad*4+r, s = s0+w*32+nf*16+n_
    #pragma unroll
    for (int mb = 0; mb < 4; ++mb)
        #pragma unroll
        for (int r = 0; r < 4; ++r) {
            int c = c0 + mb * 16 + quad * 4 + r;
            float bias = bo[c];
            #pragma unroll
            for (int nf = 0; nf < 2; ++nf) {
                size_t idx = ((size_t)b * C_ + c) * S_ + s0 + w * 32 + nf * 16 + n_;
                out[idx] = acc[nf][mb][r] + bias + x[idx];
            }
        }
}

// ---------------------------------------------------------------------------
extern "C" void kernel_launch(void* const* d_in, const int* in_sizes, int n_in,
                              void* d_out, int out_size, void* d_ws, size_t ws_size,
                              hipStream_t stream) {
    const float* x  = (const float*)d_in[0];
    const float* wp = (const float*)d_in[1];
    const float* bp = (const float*)d_in[2];
    const float* wo = (const float*)d_in[3];
    const float* bo = (const float*)d_in[4];
    float* out = (float*)d_out;

    const size_t QKV_E = (size_t)B_ * NH * S_ * DK;   // 4 Mi
    u16* q   = (u16*)d_ws;
    u16* kk  = q   + QKV_E;
    u16* vtp = kk  + QKV_E;
    u16* obf = vtp + QKV_E;                            // B*S*ND
    u16* xt  = obf + (size_t)B_ * S_ * ND;             // B*S*C
    u16* wpT = xt  + (size_t)B_ * S_ * C_;             // P3*C
    u16* woT = wpT + (size_t)P3 * C_;                  // C*ND

    transpose_all<<<dim3(16, 4, 18),             256, 0, stream>>>(x, xt, wp, wpT, wo, woT);
    qkv_mfma     <<<dim3(P3 / 64, S_ / 128, B_), 256, 0, stream>>>(xt, wpT, bp, q, kk, vtp);
    attn_mfma    <<<dim3(1024, 1, 1),            256, 0, stream>>>(q, kk, vtp, obf);
    out_proj_mfma<<<dim3(C_ / 64, S_ / 128, B_), 256, 0, stream>>>(obf, woT, bo, x, out);
}

// Round 3
// 139.944 us; speedup vs baseline: 1.0289x; 1.0289x over previous
//
#include <hip/hip_runtime.h>
#include <math.h>

#define B_  16
#define C_  256
#define S_  1024
#define NH  4
#define DK  64
#define P3  768   // 3*NH*DK
#define ND  256   // NH*DK

typedef unsigned short u16;
typedef unsigned int   u32;
typedef float  f32x4  __attribute__((ext_vector_type(4)));
typedef short  bf16x8 __attribute__((ext_vector_type(8)));

#define MFMA16(a, b, c) __builtin_amdgcn_mfma_f32_16x16x32_bf16(a, b, c, 0, 0, 0)

// fold softmax scale*log2(e) into q at projection time
#define QSCALE 0.1803368801111137f   // 0.125 * 1.44269504

// counted waitcnt + raw barrier (no vmcnt(0) drain — the __syncthreads killer)
#define WAITVM(N) asm volatile("s_waitcnt vmcnt(" #N ")" ::: "memory")
#define BARRIER() asm volatile("s_barrier" ::: "memory")

__device__ __forceinline__ u16 f2bf(float f) {
    union { float f; u32 u; } x; x.f = f;
    u32 r = x.u + 0x7fffu + ((x.u >> 16) & 1u);   // RNE
    return (u16)(r >> 16);
}

// packed f32 pair -> 2x bf16 in one VALU op (RNE)
__device__ __forceinline__ u32 cvtpk(float lo, float hi) {
    u32 r;
    asm("v_cvt_pk_bf16_f32 %0, %1, %2" : "=v"(r) : "v"(lo), "v"(hi));
    return r;
}

// async global->LDS, 16B per lane; LDS dest is wave-uniform base + lane*16
__device__ __forceinline__ void stage16(const u16* g, u16* l) {
    __builtin_amdgcn_global_load_lds(
        (const __attribute__((address_space(1))) void*)g,
        (__attribute__((address_space(3))) void*)l, 16, 0, 0);
}

// ---------------------------------------------------------------------------
// All transposes in ONE launch:
//   z in [0,16): x slice z: [256][1024] -> xt [1024][256] (fp32->bf16)
//   z == 16:     w_proj [256][768] -> wpT [768][256]
//   z == 17:     w_out  [256][256] -> woT [256][256]
// ---------------------------------------------------------------------------
__global__ __launch_bounds__(256) void transpose_all(
    const float* __restrict__ x, u16* __restrict__ xt,
    const float* __restrict__ wp, u16* __restrict__ wpT,
    const float* __restrict__ wo, u16* __restrict__ woT)
{
    const int z = blockIdx.z;
    const float* src;
    u16* dst;
    int Cc;
    if (z < 16)       { src = x + (size_t)z * C_ * S_; dst = xt + (size_t)z * C_ * S_; Cc = S_; }
    else if (z == 16) { src = wp; dst = wpT; Cc = P3; }
    else              { src = wo; dst = woT; Cc = ND; }
    if ((int)blockIdx.x * 64 >= Cc) return;
    const int R = C_;   // 256 rows for all three

    __shared__ float T[64][65];
    const int tid = threadIdx.x;
    const int c0 = blockIdx.x * 64, r0 = blockIdx.y * 64;

    const int l64 = tid & 63, rr0 = tid >> 6;
    #pragma unroll
    for (int t = 0; t < 16; ++t) {
        int rr = rr0 + t * 4;
        T[rr][l64] = src[(size_t)(r0 + rr) * Cc + c0 + l64];
    }
    __syncthreads();
    const int rp = tid & 31;
    const int cb = tid >> 5;
    #pragma unroll
    for (int t = 0; t < 8; ++t) {
        int c = cb + t * 8;
        u32 lo = f2bf(T[2 * rp][c]);
        u32 hi = f2bf(T[2 * rp + 1][c]);
        *(u32*)&dst[(size_t)(c0 + c) * R + r0 + 2 * rp] = lo | (hi << 16);
    }
}

// ---------------------------------------------------------------------------
// QKV projection: 128(M=s) x 64(N=n) tile, 4 waves x (32x64).
// BK=64, 4 phases, double-buffered LDS prefetch (counted vmcnt, raw barriers).
// q gets QSCALE folded in. v stored TRANSPOSED [bh][dk][s].
// ---------------------------------------------------------------------------
__global__ __launch_bounds__(256) void qkv_mfma(
    const u16* __restrict__ xt, const u16* __restrict__ wpT,
    const float* __restrict__ bp, u16* __restrict__ qo,
    u16* __restrict__ ko, u16* __restrict__ vo)
{
    // 2 x (As 8192 [128 rows x 64 k] + Bs 4096 [64 rows x 64 k]) = 48 KB
    __shared__ __align__(16) u16 SM[24576];

    const int tid = threadIdx.x;
    const int w = tid >> 6, lane = tid & 63;
    const int n_ = lane & 15, quad = lane >> 4;
    const int n0 = blockIdx.x * 64, s0 = blockIdx.y * 128, b = blockIdx.z;

    const u16* ar0 = xt + ((size_t)b * S_ + s0 + (2 * w + 0) * 16 + n_) * C_ + quad * 8;
    const u16* ar1 = xt + ((size_t)b * S_ + s0 + (2 * w + 1) * 16 + n_) * C_ + quad * 8;
    const u16* br  = wpT + (size_t)(n0 + w * 16 + n_) * C_ + quad * 8;

    f32x4 acc[2][4];
    #pragma unroll
    for (int am = 0; am < 2; ++am)
        #pragma unroll
        for (int nf = 0; nf < 4; ++nf)
            #pragma unroll
            for (int r = 0; r < 4; ++r) acc[am][nf][r] = 0.f;

    // prologue: stage phase 0 into buf 0 (6 loads/wave)
    {
        u16* As_ = SM;
        u16* Bs_ = SM + 8192;
        stage16(ar0,      As_ + (4 * w + 0) * 512);
        stage16(ar0 + 32, As_ + (4 * w + 1) * 512);
        stage16(ar1,      As_ + (4 * w + 2) * 512);
        stage16(ar1 + 32, As_ + (4 * w + 3) * 512);
        stage16(br,       Bs_ + (2 * w + 0) * 512);
        stage16(br + 32,  Bs_ + (2 * w + 1) * 512);
    }

    #pragma unroll
    for (int p = 0; p < 4; ++p) {
        u16* As_ = SM + (p & 1) * 12288;
        u16* Bs_ = As_ + 8192;
        if (p < 3) {
            const int pk = (p + 1) * 64;
            u16* An = SM + ((p + 1) & 1) * 12288;
            u16* Bn = An + 8192;
            stage16(ar0 + pk,      An + (4 * w + 0) * 512);
            stage16(ar0 + pk + 32, An + (4 * w + 1) * 512);
            stage16(ar1 + pk,      An + (4 * w + 2) * 512);
            stage16(ar1 + pk + 32, An + (4 * w + 3) * 512);
            stage16(br  + pk,      Bn + (2 * w + 0) * 512);
            stage16(br  + pk + 32, Bn + (2 * w + 1) * 512);
            WAITVM(6);   // phase-p loads done; p+1's 6 stay in flight
        } else {
            WAITVM(0);
        }
        BARRIER();
        #pragma unroll
        for (int kc = 0; kc < 2; ++kc) {
            bf16x8 af0 = *(const bf16x8*)&As_[((2 * w + 0) * 2 + kc) * 512 + lane * 8];
            bf16x8 af1 = *(const bf16x8*)&As_[((2 * w + 1) * 2 + kc) * 512 + lane * 8];
            #pragma unroll
            for (int nf = 0; nf < 4; ++nf) {
                bf16x8 bf = *(const bf16x8*)&Bs_[(nf * 2 + kc) * 512 + lane * 8];
                acc[0][nf] = MFMA16(af0, bf, acc[0][nf]);
                acc[1][nf] = MFMA16(af1, bf, acc[1][nf]);
            }
        }
        if (p < 3) BARRIER();   // all waves done reading buf before restage
    }

    const int hd = n0 / 192, rem = n0 % 192, which = rem / 64;
    const int bh = b * NH + hd;
    float bias[4];
    #pragma unroll
    for (int nf = 0; nf < 4; ++nf) bias[nf] = bp[n0 + nf * 16 + n_];
    const float sc = (which == 0) ? QSCALE : 1.f;

    __syncthreads();   // full drain once; reuse SM for epilogue
    if (which < 2) {
        u16* Cs = SM;                      // [128][72]
        #pragma unroll
        for (int am = 0; am < 2; ++am) {
            int row0 = w * 32 + am * 16 + quad * 4;
            #pragma unroll
            for (int nf = 0; nf < 4; ++nf)
                #pragma unroll
                for (int r = 0; r < 4; ++r)
                    Cs[(row0 + r) * 72 + nf * 16 + n_] =
                        f2bf((acc[am][nf][r] + bias[nf]) * sc);
        }
        __syncthreads();
        u16* dst = (which == 0) ? qo : ko;
        #pragma unroll
        for (int t = 0; t < 4; ++t) {
            int ii = tid + t * 256;
            int row = ii >> 3, c8 = (ii & 7) * 8;
            *(bf16x8*)&dst[((size_t)bh * S_ + s0 + row) * DK + c8] =
                *(const bf16x8*)&Cs[row * 72 + c8];
        }
    } else {
        u16* Cs = SM;                      // [64][136] (dk-major, plain s cols)
        #pragma unroll
        for (int am = 0; am < 2; ++am) {
            int colb = w * 32 + am * 16 + quad * 4;
            #pragma unroll
            for (int nf = 0; nf < 4; ++nf)
                #pragma unroll
                for (int r = 0; r < 4; ++r)
                    Cs[(nf * 16 + n_) * 136 + colb + r] =
                        f2bf(acc[am][nf][r] + bias[nf]);
        }
        __syncthreads();
        #pragma unroll
        for (int t = 0; t < 4; ++t) {
            int ii = tid + t * 256;
            int row = ii >> 4, c8 = (ii & 15) * 8;
            *(bf16x8*)&vo[((size_t)bh * DK + row) * S_ + s0 + c8] =
                *(const bf16x8*)&Cs[row * 136 + c8];
        }
    }
}

// ---------------------------------------------------------------------------
// Flash attention: block = 128 q (4 waves x 32 q), 64-key tiles, no-max
// softmax. S computed TRANSPOSED (A=K with kappa-permuted rows, B=Q) so the
// P^T C-layout -> PV B-operand transform is a pure register repack.
// RING-4 LDS (64 KB), prefetch depth 2, ONE barrier per tile, counted vmcnt.
// Bijective XCD swizzle: 64-block chunks per XCD = 8 full heads -> K/V L2-fit.
// ---------------------------------------------------------------------------
__global__ __launch_bounds__(256) void attn_mfma(
    const u16* __restrict__ q, const u16* __restrict__ k,
    const u16* __restrict__ vt, u16* __restrict__ obf)
{
    // ring of 4 x (Ks 4096 u16 + Vs 4096 u16) = 64 KB; epilogue reuses SM
    __shared__ __align__(16) u16 SM[32768];

    const int tid = threadIdx.x;
    const int w = tid >> 6, lane = tid & 63;
    const int n_ = lane & 15, quad = lane >> 4;

    // XCD swizzle: 512 blocks, 8 XCDs, 64-block chunks (8 complete heads/XCD)
    const int id  = blockIdx.x;
    const int nid = (id & 7) * 64 + (id >> 3);
    const int i0  = (nid & 7) * 128;
    const int bh  = nid >> 3;
    const int hd  = bh & 3;
    const int b   = bh >> 2;

    // Q fragments (B-operand; scale pre-folded): query = i0 + w*32 + am*16 + n_
    bf16x8 qf[2][2];
    #pragma unroll
    for (int am = 0; am < 2; ++am) {
        const u16* qrow = q + ((size_t)bh * S_ + i0 + w * 32 + am * 16 + n_) * DK;
        qf[am][0] = *(const bf16x8*)&qrow[quad * 8];
        qf[am][1] = *(const bf16x8*)&qrow[32 + quad * 8];
    }

    // K staging with kappa row permutation (staging wave w = MFMA block nb)
    const int kappa = 32 * (w & 1) + 8 * (n_ >> 2) + 4 * (w >> 1) + (n_ & 3);
    const u16* kbase = k  + ((size_t)bh * S_ + kappa) * DK + quad * 8;
    const u16* vbase = vt + ((size_t)bh * DK + w * 16 + n_) * S_ + quad * 8;

    float lsum[2] = {0.f, 0.f};
    f32x4 oacc[2][4];
    #pragma unroll
    for (int am = 0; am < 2; ++am)
        #pragma unroll
        for (int nd = 0; nd < 4; ++nd)
            #pragma unroll
            for (int r = 0; r < 4; ++r) oacc[am][nd][r] = 0.f;

    // prologue: tiles 0 and 1 into slots 0 and 1 (8 loads/wave)
    stage16(kbase,                SM + w * 1024);
    stage16(kbase + 32,           SM + w * 1024 + 512);
    stage16(vbase,                SM + 4096 + w * 1024);
    stage16(vbase + 32,           SM + 4096 + w * 1024 + 512);
    stage16(kbase + 64 * DK,      SM + 8192 + w * 1024);
    stage16(kbase + 64 * DK + 32, SM + 8192 + w * 1024 + 512);
    stage16(vbase + 64,           SM + 8192 + 4096 + w * 1024);
    stage16(vbase + 64 + 32,      SM + 8192 + 4096 + w * 1024 + 512);

    for (int t = 0; t < 16; ++t) {
        u16* Ks = SM + (t & 3) * 8192;
        u16* Vs = Ks + 4096;
        if (t < 14) {
            // stage tile t+2 into slot (t+2)&3 — safe: all waves passed
            // barrier(t-1) => finished reading slot (t-2)&3 == (t+2)&3
            const size_t jn = (size_t)(t + 2) * 64;
            u16* Kn = SM + ((t + 2) & 3) * 8192;
            u16* Vn = Kn + 4096;
            stage16(kbase + jn * DK,      Kn + w * 1024);
            stage16(kbase + jn * DK + 32, Kn + w * 1024 + 512);
            stage16(vbase + jn,           Vn + w * 1024);
            stage16(vbase + jn + 32,      Vn + w * 1024 + 512);
            WAITVM(8);   // tile-t landed; t+1 and t+2 (8 loads) in flight
        } else if (t == 14) {
            WAITVM(4);   // tile-14 landed; tile-15's 4 in flight
        } else {
            WAITVM(0);
        }
        BARRIER();       // single barrier per tile

        // S^T = K Q^T : C rows = permuted keys, cols = queries (n_)
        f32x4 sb[2][4];
        __builtin_amdgcn_s_setprio(1);
        #pragma unroll
        for (int nb = 0; nb < 4; ++nb) {
            bf16x8 kf0 = *(const bf16x8*)&Ks[nb * 1024 + lane * 8];
            bf16x8 kf1 = *(const bf16x8*)&Ks[nb * 1024 + 512 + lane * 8];
            #pragma unroll
            for (int am = 0; am < 2; ++am) {
                f32x4 a; a[0] = a[1] = a[2] = a[3] = 0.f;
                a = MFMA16(kf0, qf[am][0], a);
                a = MFMA16(kf1, qf[am][1], a);
                sb[am][nb] = a;
            }
        }
        __builtin_amdgcn_s_setprio(0);

        // exp2 (f32), sum, packed-convert into PV B-operand layout
        bf16x8 pa[2][2];
        #pragma unroll
        for (int am = 0; am < 2; ++am) {
            float pr[4][4];
            #pragma unroll
            for (int nb = 0; nb < 4; ++nb)
                #pragma unroll
                for (int r = 0; r < 4; ++r) {
                    float p = exp2f(sb[am][nb][r]);
                    lsum[am] += p;
                    pr[nb][r] = p;
                }
            union { bf16x8 v; u32 u[4]; } p0, p1;
            p0.u[0] = cvtpk(pr[0][0], pr[0][1]);
            p0.u[1] = cvtpk(pr[0][2], pr[0][3]);
            p0.u[2] = cvtpk(pr[2][0], pr[2][1]);
            p0.u[3] = cvtpk(pr[2][2], pr[2][3]);
            p1.u[0] = cvtpk(pr[1][0], pr[1][1]);
            p1.u[1] = cvtpk(pr[1][2], pr[1][3]);
            p1.u[2] = cvtpk(pr[3][0], pr[3][1]);
            p1.u[3] = cvtpk(pr[3][2], pr[3][3]);
            pa[am][0] = p0.v;
            pa[am][1] = p1.v;
        }

        // O^T += V^T P^T : A = V^T frags (key-slots identity), B = pa
        __builtin_amdgcn_s_setprio(1);
        #pragma unroll
        for (int nd = 0; nd < 4; ++nd) {
            bf16x8 vf0 = *(const bf16x8*)&Vs[nd * 1024 + lane * 8];
            bf16x8 vf1 = *(const bf16x8*)&Vs[nd * 1024 + 512 + lane * 8];
            #pragma unroll
            for (int am = 0; am < 2; ++am) {
                oacc[am][nd] = MFMA16(vf0, pa[am][0], oacc[am][nd]);
                oacc[am][nd] = MFMA16(vf1, pa[am][1], oacc[am][nd]);
            }
        }
        __builtin_amdgcn_s_setprio(0);
    }

    // total = sum over 4 quads (all 16 in-lane values are for query n_)
    float inv[2];
    #pragma unroll
    for (int am = 0; am < 2; ++am) {
        float s = lsum[am];
        s += __shfl_xor(s, 16);
        s += __shfl_xor(s, 32);
        inv[am] = 1.f / s;
    }

    // epilogue: O^T[dk=nd*16+quad*4+r][query=n_] -> eb[query-local][dk]
    __syncthreads();   // full drain once; reuse SM
    u16* eb = SM + w * 2304;   // [32][72]
    #pragma unroll
    for (int am = 0; am < 2; ++am)
        #pragma unroll
        for (int nd = 0; nd < 4; ++nd) {
            uint2 uv;
            uv.x = cvtpk(oacc[am][nd][0] * inv[am], oacc[am][nd][1] * inv[am]);
            uv.y = cvtpk(oacc[am][nd][2] * inv[am], oacc[am][nd][3] * inv[am]);
            *(uint2*)&eb[(am * 16 + n_) * 72 + nd * 16 + quad * 4] = uv;
        }
    __syncthreads();
    #pragma unroll
    for (int t = 0; t < 4; ++t) {
        int ii = lane + t * 64;
        int row = ii >> 3, c8 = (ii & 7) * 8;
        *(bf16x8*)&obf[((size_t)b * S_ + i0 + w * 32 + row) * ND + hd * DK + c8] =
            *(const bf16x8*)&eb[row * 72 + c8];
    }
}

// ---------------------------------------------------------------------------
// Out projection: A = woT (M=c=64), B = obf (N=s=128).
// BK=64, 4 phases, double-buffered prefetch like qkv.
// C[c][s] layout -> direct coalesced stores out[b][c][s] (+bias+residual).
// ---------------------------------------------------------------------------
__global__ __launch_bounds__(256) void out_proj_mfma(
    const u16* __restrict__ obf, const u16* __restrict__ woT,
    const float* __restrict__ bo, const float* __restrict__ x,
    float* __restrict__ out)
{
    // 2 x (Bs 8192 [128 rows x 64 k] + As 4096 [64 rows x 64 k]) = 48 KB
    __shared__ __align__(16) u16 SM[24576];

    const int tid = threadIdx.x;
    const int w = tid >> 6, lane = tid & 63;
    const int n_ = lane & 15, quad = lane >> 4;
    const int c0 = blockIdx.x * 64, s0 = blockIdx.y * 128, b = blockIdx.z;

    const u16* ar  = woT + (size_t)(c0 + w * 16 + n_) * ND + quad * 8;
    const u16* br0 = obf + ((size_t)b * S_ + s0 + (2 * w + 0) * 16 + n_) * ND + quad * 8;
    const u16* br1 = obf + ((size_t)b * S_ + s0 + (2 * w + 1) * 16 + n_) * ND + quad * 8;

    f32x4 acc[2][4];
    #pragma unroll
    for (int nf = 0; nf < 2; ++nf)
        #pragma unroll
        for (int mb = 0; mb < 4; ++mb)
            #pragma unroll
            for (int r = 0; r < 4; ++r) acc[nf][mb][r] = 0.f;

    // prologue: stage phase 0 into buf 0
    {
        u16* Bs_ = SM;
        u16* As_ = SM + 8192;
        stage16(br0,      Bs_ + (4 * w + 0) * 512);
        stage16(br0 + 32, Bs_ + (4 * w + 1) * 512);
        stage16(br1,      Bs_ + (4 * w + 2) * 512);
        stage16(br1 + 32, Bs_ + (4 * w + 3) * 512);
        stage16(ar,       As_ + (2 * w + 0) * 512);
        stage16(ar + 32,  As_ + (2 * w + 1) * 512);
    }

    #pragma unroll
    for (int p = 0; p < 4; ++p) {
        u16* Bs_ = SM + (p & 1) * 12288;
        u16* As_ = Bs_ + 8192;
        if (p < 3) {
            const int pk = (p + 1) * 64;
            u16* Bn = SM + ((p + 1) & 1) * 12288;
            u16* An = Bn + 8192;
            stage16(br0 + pk,      Bn + (4 * w + 0) * 512);
            stage16(br0 + pk + 32, Bn + (4 * w + 1) * 512);
            stage16(br1 + pk,      Bn + (4 * w + 2) * 512);
            stage16(br1 + pk + 32, Bn + (4 * w + 3) * 512);
            stage16(ar  + pk,      An + (2 * w + 0) * 512);
            stage16(ar  + pk + 32, An + (2 * w + 1) * 512);
            WAITVM(6);
        } else {
            WAITVM(0);
        }
        BARRIER();
        #pragma unroll
        for (int kc = 0; kc < 2; ++kc) {
            bf16x8 bf0 = *(const bf16x8*)&Bs_[((2 * w + 0) * 2 + kc) * 512 + lane * 8];
            bf16x8 bf1 = *(const bf16x8*)&Bs_[((2 * w + 1) * 2 + kc) * 512 + lane * 8];
            #pragma unroll
            for (int mb = 0; mb < 4; ++mb) {
                bf16x8 af = *(const bf16x8*)&As_[(mb * 2 + kc) * 512 + lane * 8];
                acc[0][mb] = MFMA16(af, bf0, acc[0][mb]);
                acc[1][mb] = MFMA16(af, bf1, acc[1][mb]);
            }
        }
        if (p < 3) BARRIER();
    }

    // direct epilogue: c = c0+mb*16+quad*4+r, s = s0+w*32+nf*16+n_
    #pragma unroll
    for (int mb = 0; mb < 4; ++mb)
        #pragma unroll
        for (int r = 0; r < 4; ++r) {
            int c = c0 + mb * 16 + quad * 4 + r;
            float bias = bo[c];
            #pragma unroll
            for (int nf = 0; nf < 2; ++nf) {
                size_t idx = ((size_t)b * C_ + c) * S_ + s0 + w * 32 + nf * 16 + n_;
                out[idx] = acc[nf][mb][r] + bias + x[idx];
            }
        }
}

// ---------------------------------------------------------------------------
extern "C" void kernel_launch(void* const* d_in, const int* in_sizes, int n_in,
                              void* d_out, int out_size, void* d_ws, size_t ws_size,
                              hipStream_t stream) {
    const float* x  = (const float*)d_in[0];
    const float* wp = (const float*)d_in[1];
    const float* bp = (const float*)d_in[2];
    const float* wo = (const float*)d_in[3];
    const float* bo = (const float*)d_in[4];
    float* out = (float*)d_out;

    const size_t QKV_E = (size_t)B_ * NH * S_ * DK;   // 4 Mi
    u16* q   = (u16*)d_ws;
    u16* kk  = q   + QKV_E;
    u16* vtp = kk  + QKV_E;
    u16* obf = vtp + QKV_E;                            // B*S*ND
    u16* xt  = obf + (size_t)B_ * S_ * ND;             // B*S*C
    u16* wpT = xt  + (size_t)B_ * S_ * C_;             // P3*C
    u16* woT = wpT + (size_t)P3 * C_;                  // C*ND

    transpose_all<<<dim3(16, 4, 18),             256, 0, stream>>>(x, xt, wp, wpT, wo, woT);
    qkv_mfma     <<<dim3(P3 / 64, S_ / 128, B_), 256, 0, stream>>>(xt, wpT, bp, q, kk, vtp);
    attn_mfma    <<<dim3(512, 1, 1),             256, 0, stream>>>(q, kk, vtp, obf);
    out_proj_mfma<<<dim3(C_ / 64, S_ / 128, B_), 256, 0, stream>>>(obf, woT, bo, x, out);
}

// Round 4
// 128.773 us; speedup vs baseline: 1.1182x; 1.0868x over previous
//
#include <hip/hip_runtime.h>
#include <math.h>

#define B_  16
#define C_  256
#define S_  1024
#define NH  4
#define DK  64
#define P3  768   // 3*NH*DK
#define ND  256   // NH*DK

typedef unsigned short u16;
typedef unsigned int   u32;
typedef float  f32x4  __attribute__((ext_vector_type(4)));
typedef short  bf16x8 __attribute__((ext_vector_type(8)));

#define MFMA16(a, b, c) __builtin_amdgcn_mfma_f32_16x16x32_bf16(a, b, c, 0, 0, 0)

// fold softmax scale*log2(e) into q at projection time
#define QSCALE 0.1803368801111137f   // 0.125 * 1.44269504

// counted waitcnt + raw barrier (no vmcnt(0) drain — the __syncthreads killer)
#define WAITVM(N) asm volatile("s_waitcnt vmcnt(" #N ")" ::: "memory")
#define BARRIER() asm volatile("s_barrier" ::: "memory")

#if __has_builtin(__builtin_amdgcn_exp2f)
#define EXP2F(x) __builtin_amdgcn_exp2f(x)
#else
#define EXP2F(x) exp2f(x)
#endif

__device__ __forceinline__ u16 f2bf(float f) {
    union { float f; u32 u; } x; x.f = f;
    u32 r = x.u + 0x7fffu + ((x.u >> 16) & 1u);   // RNE
    return (u16)(r >> 16);
}

// packed f32 pair -> 2x bf16 in one VALU op (RNE)
__device__ __forceinline__ u32 cvtpk(float lo, float hi) {
    u32 r;
    asm("v_cvt_pk_bf16_f32 %0, %1, %2" : "=v"(r) : "v"(lo), "v"(hi));
    return r;
}

// async global->LDS, 16B per lane; LDS dest is wave-uniform base + lane*16
__device__ __forceinline__ void stage16(const u16* g, u16* l) {
    __builtin_amdgcn_global_load_lds(
        (const __attribute__((address_space(1))) void*)g,
        (__attribute__((address_space(3))) void*)l, 16, 0, 0);
}

// ---------------------------------------------------------------------------
// All transposes in ONE launch:
//   z in [0,16): x slice z: [256][1024] -> xt [1024][256] (fp32->bf16)
//   z == 16:     w_proj [256][768] -> wpT [768][256]
//   z == 17:     w_out  [256][256] -> woT [256][256]
// ---------------------------------------------------------------------------
__global__ __launch_bounds__(256) void transpose_all(
    const float* __restrict__ x, u16* __restrict__ xt,
    const float* __restrict__ wp, u16* __restrict__ wpT,
    const float* __restrict__ wo, u16* __restrict__ woT)
{
    const int z = blockIdx.z;
    const float* src;
    u16* dst;
    int Cc;
    if (z < 16)       { src = x + (size_t)z * C_ * S_; dst = xt + (size_t)z * C_ * S_; Cc = S_; }
    else if (z == 16) { src = wp; dst = wpT; Cc = P3; }
    else              { src = wo; dst = woT; Cc = ND; }
    if ((int)blockIdx.x * 64 >= Cc) return;
    const int R = C_;   // 256 rows for all three

    __shared__ float T[64][65];
    const int tid = threadIdx.x;
    const int c0 = blockIdx.x * 64, r0 = blockIdx.y * 64;

    const int l64 = tid & 63, rr0 = tid >> 6;
    #pragma unroll
    for (int t = 0; t < 16; ++t) {
        int rr = rr0 + t * 4;
        T[rr][l64] = src[(size_t)(r0 + rr) * Cc + c0 + l64];
    }
    __syncthreads();
    const int rp = tid & 31;
    const int cb = tid >> 5;
    #pragma unroll
    for (int t = 0; t < 8; ++t) {
        int c = cb + t * 8;
        u32 lo = f2bf(T[2 * rp][c]);
        u32 hi = f2bf(T[2 * rp + 1][c]);
        *(u32*)&dst[(size_t)(c0 + c) * R + r0 + 2 * rp] = lo | (hi << 16);
    }
}

// ---------------------------------------------------------------------------
// QKV projection: 128(M=s) x 64(N=n) tile, 4 waves x (32x64).
// BK=64, 4 phases, double-buffered LDS prefetch (counted vmcnt, raw barriers).
// q gets QSCALE folded in. v stored TRANSPOSED [bh][dk][s].
// ---------------------------------------------------------------------------
__global__ __launch_bounds__(256) void qkv_mfma(
    const u16* __restrict__ xt, const u16* __restrict__ wpT,
    const float* __restrict__ bp, u16* __restrict__ qo,
    u16* __restrict__ ko, u16* __restrict__ vo)
{
    // 2 x (As 8192 [128 rows x 64 k] + Bs 4096 [64 rows x 64 k]) = 48 KB
    __shared__ __align__(16) u16 SM[24576];

    const int tid = threadIdx.x;
    const int w = tid >> 6, lane = tid & 63;
    const int n_ = lane & 15, quad = lane >> 4;
    const int n0 = blockIdx.x * 64, s0 = blockIdx.y * 128, b = blockIdx.z;

    const u16* ar0 = xt + ((size_t)b * S_ + s0 + (2 * w + 0) * 16 + n_) * C_ + quad * 8;
    const u16* ar1 = xt + ((size_t)b * S_ + s0 + (2 * w + 1) * 16 + n_) * C_ + quad * 8;
    const u16* br  = wpT + (size_t)(n0 + w * 16 + n_) * C_ + quad * 8;

    f32x4 acc[2][4];
    #pragma unroll
    for (int am = 0; am < 2; ++am)
        #pragma unroll
        for (int nf = 0; nf < 4; ++nf)
            #pragma unroll
            for (int r = 0; r < 4; ++r) acc[am][nf][r] = 0.f;

    // prologue: stage phase 0 into buf 0 (6 loads/wave)
    {
        u16* As_ = SM;
        u16* Bs_ = SM + 8192;
        stage16(ar0,      As_ + (4 * w + 0) * 512);
        stage16(ar0 + 32, As_ + (4 * w + 1) * 512);
        stage16(ar1,      As_ + (4 * w + 2) * 512);
        stage16(ar1 + 32, As_ + (4 * w + 3) * 512);
        stage16(br,       Bs_ + (2 * w + 0) * 512);
        stage16(br + 32,  Bs_ + (2 * w + 1) * 512);
    }

    #pragma unroll
    for (int p = 0; p < 4; ++p) {
        u16* As_ = SM + (p & 1) * 12288;
        u16* Bs_ = As_ + 8192;
        if (p < 3) {
            const int pk = (p + 1) * 64;
            u16* An = SM + ((p + 1) & 1) * 12288;
            u16* Bn = An + 8192;
            stage16(ar0 + pk,      An + (4 * w + 0) * 512);
            stage16(ar0 + pk + 32, An + (4 * w + 1) * 512);
            stage16(ar1 + pk,      An + (4 * w + 2) * 512);
            stage16(ar1 + pk + 32, An + (4 * w + 3) * 512);
            stage16(br  + pk,      Bn + (2 * w + 0) * 512);
            stage16(br  + pk + 32, Bn + (2 * w + 1) * 512);
            WAITVM(6);   // phase-p loads done; p+1's 6 stay in flight
        } else {
            WAITVM(0);
        }
        BARRIER();
        #pragma unroll
        for (int kc = 0; kc < 2; ++kc) {
            bf16x8 af0 = *(const bf16x8*)&As_[((2 * w + 0) * 2 + kc) * 512 + lane * 8];
            bf16x8 af1 = *(const bf16x8*)&As_[((2 * w + 1) * 2 + kc) * 512 + lane * 8];
            #pragma unroll
            for (int nf = 0; nf < 4; ++nf) {
                bf16x8 bf = *(const bf16x8*)&Bs_[(nf * 2 + kc) * 512 + lane * 8];
                acc[0][nf] = MFMA16(af0, bf, acc[0][nf]);
                acc[1][nf] = MFMA16(af1, bf, acc[1][nf]);
            }
        }
        if (p < 3) BARRIER();   // all waves done reading buf before restage
    }

    const int hd = n0 / 192, rem = n0 % 192, which = rem / 64;
    const int bh = b * NH + hd;
    float bias[4];
    #pragma unroll
    for (int nf = 0; nf < 4; ++nf) bias[nf] = bp[n0 + nf * 16 + n_];
    const float sc = (which == 0) ? QSCALE : 1.f;

    __syncthreads();   // full drain once; reuse SM for epilogue
    if (which < 2) {
        u16* Cs = SM;                      // [128][72]
        #pragma unroll
        for (int am = 0; am < 2; ++am) {
            int row0 = w * 32 + am * 16 + quad * 4;
            #pragma unroll
            for (int nf = 0; nf < 4; ++nf)
                #pragma unroll
                for (int r = 0; r < 4; ++r)
                    Cs[(row0 + r) * 72 + nf * 16 + n_] =
                        f2bf((acc[am][nf][r] + bias[nf]) * sc);
        }
        __syncthreads();
        u16* dst = (which == 0) ? qo : ko;
        #pragma unroll
        for (int t = 0; t < 4; ++t) {
            int ii = tid + t * 256;
            int row = ii >> 3, c8 = (ii & 7) * 8;
            *(bf16x8*)&dst[((size_t)bh * S_ + s0 + row) * DK + c8] =
                *(const bf16x8*)&Cs[row * 72 + c8];
        }
    } else {
        u16* Cs = SM;                      // [64][136] (dk-major, plain s cols)
        #pragma unroll
        for (int am = 0; am < 2; ++am) {
            int colb = w * 32 + am * 16 + quad * 4;
            #pragma unroll
            for (int nf = 0; nf < 4; ++nf)
                #pragma unroll
                for (int r = 0; r < 4; ++r)
                    Cs[(nf * 16 + n_) * 136 + colb + r] =
                        f2bf(acc[am][nf][r] + bias[nf]);
        }
        __syncthreads();
        #pragma unroll
        for (int t = 0; t < 4; ++t) {
            int ii = tid + t * 256;
            int row = ii >> 4, c8 = (ii & 15) * 8;
            *(bf16x8*)&vo[((size_t)bh * DK + row) * S_ + s0 + c8] =
                *(const bf16x8*)&Cs[row * 136 + c8];
        }
    }
}

// ---------------------------------------------------------------------------
// Flash attention: block = 128 q (4 waves x 32 q), 64-key tiles, no-max
// softmax. S computed TRANSPOSED (A=K with kappa-permuted rows, B=Q) so the
// P^T C-layout -> PV B-operand transform is a pure register repack.
// T15 2-tile pipeline: iter t = QK(t) MFMA -> PV(t-1) MFMA (independent of
// softmax(t), fills matrix pipe while VALU runs) -> softmax(t) -> pa.
// Row-sum via ones-MFMA (all C rows = key-sum per query; no shuffles).
// Ring-4 LDS, staging AFTER the barrier (slot rewrite ordered after last
// read: slot s read at iters s (K) and s+1 (V), rewritten iter s+2
// post-barrier). Steady-state vmcnt(4). Bijective XCD swizzle.
// ---------------------------------------------------------------------------
__global__ __launch_bounds__(256) void attn_mfma(
    const u16* __restrict__ q, const u16* __restrict__ k,
    const u16* __restrict__ vt, u16* __restrict__ obf)
{
    // ring of 4 x (Ks 4096 u16 + Vs 4096 u16) = 64 KB; epilogue reuses SM
    __shared__ __align__(16) u16 SM[32768];

    const int tid = threadIdx.x;
    const int w = tid >> 6, lane = tid & 63;
    const int n_ = lane & 15, quad = lane >> 4;

    // XCD swizzle: 512 blocks, 8 XCDs, 64-block chunks (8 complete heads/XCD)
    const int id  = blockIdx.x;
    const int nid = (id & 7) * 64 + (id >> 3);
    const int i0  = (nid & 7) * 128;
    const int bh  = nid >> 3;
    const int hd  = bh & 3;
    const int b   = bh >> 2;

    // Q fragments (B-operand; scale pre-folded): query = i0 + w*32 + am*16 + n_
    bf16x8 qf[2][2];
    #pragma unroll
    for (int am = 0; am < 2; ++am) {
        const u16* qrow = q + ((size_t)bh * S_ + i0 + w * 32 + am * 16 + n_) * DK;
        qf[am][0] = *(const bf16x8*)&qrow[quad * 8];
        qf[am][1] = *(const bf16x8*)&qrow[32 + quad * 8];
    }

    // all-ones bf16 A-fragment for the row-sum MFMA (layout-independent)
    union { bf16x8 v; u32 u[4]; } ones_;
    #pragma unroll
    for (int i = 0; i < 4; ++i) ones_.u[i] = 0x3F803F80u;
    const bf16x8 onesf = ones_.v;

    // K staging with kappa row permutation (staging wave w = MFMA block nb)
    const int kappa = 32 * (w & 1) + 8 * (n_ >> 2) + 4 * (w >> 1) + (n_ & 3);
    const u16* kbase = k  + ((size_t)bh * S_ + kappa) * DK + quad * 8;
    const u16* vbase = vt + ((size_t)bh * DK + w * 16 + n_) * S_ + quad * 8;

    f32x4 oacc[2][4];
    f32x4 acc_sum[2];
    #pragma unroll
    for (int am = 0; am < 2; ++am) {
        #pragma unroll
        for (int nd = 0; nd < 4; ++nd)
            #pragma unroll
            for (int r = 0; r < 4; ++r) oacc[am][nd][r] = 0.f;
        #pragma unroll
        for (int r = 0; r < 4; ++r) acc_sum[am][r] = 0.f;
    }

    // prologue: tiles 0 and 1 into slots 0 and 1 (8 loads/wave)
    stage16(kbase,                SM + w * 1024);
    stage16(kbase + 32,           SM + w * 1024 + 512);
    stage16(vbase,                SM + 4096 + w * 1024);
    stage16(vbase + 32,           SM + 4096 + w * 1024 + 512);
    stage16(kbase + 64 * DK,      SM + 8192 + w * 1024);
    stage16(kbase + 64 * DK + 32, SM + 8192 + w * 1024 + 512);
    stage16(vbase + 64,           SM + 8192 + 4096 + w * 1024);
    stage16(vbase + 64 + 32,      SM + 8192 + 4096 + w * 1024 + 512);

    bf16x8 pa[2][2];   // packed P of the PREVIOUS tile (valid for t >= 1)

    for (int t = 0; t < 16; ++t) {
        u16* Ks = SM + (t & 3) * 8192;
        u16* Vp = SM + ((t + 3) & 3) * 8192 + 4096;   // Vs of tile t-1
        if (t < 15) WAITVM(4); else WAITVM(0);
        BARRIER();
        if (t < 14) {
            // stage tile t+2 into slot (t+2)&3 AFTER the barrier:
            // ordered after all waves finished iter t-1 (last read of slot)
            const size_t jn = (size_t)(t + 2) * 64;
            u16* Kn = SM + ((t + 2) & 3) * 8192;
            u16* Vn = Kn + 4096;
            stage16(kbase + jn * DK,      Kn + w * 1024);
            stage16(kbase + jn * DK + 32, Kn + w * 1024 + 512);
            stage16(vbase + jn,           Vn + w * 1024);
            stage16(vbase + jn + 32,      Vn + w * 1024 + 512);
        }

        // S^T(t) = K Q^T : C rows = permuted keys, cols = queries (n_)
        f32x4 sb[2][4];
        __builtin_amdgcn_s_setprio(1);
        #pragma unroll
        for (int nb = 0; nb < 4; ++nb) {
            bf16x8 kf0 = *(const bf16x8*)&Ks[nb * 1024 + lane * 8];
            bf16x8 kf1 = *(const bf16x8*)&Ks[nb * 1024 + 512 + lane * 8];
            #pragma unroll
            for (int am = 0; am < 2; ++am) {
                f32x4 a; a[0] = a[1] = a[2] = a[3] = 0.f;
                a = MFMA16(kf0, qf[am][0], a);
                a = MFMA16(kf1, qf[am][1], a);
                sb[am][nb] = a;
            }
        }

        // PV(t-1): independent of sb(t) -> overlaps softmax below.
        // O^T += V^T P^T ; row-sum via ones-MFMA into acc_sum.
        if (t > 0) {
            #pragma unroll
            for (int nd = 0; nd < 4; ++nd) {
                bf16x8 vf0 = *(const bf16x8*)&Vp[nd * 1024 + lane * 8];
                bf16x8 vf1 = *(const bf16x8*)&Vp[nd * 1024 + 512 + lane * 8];
                #pragma unroll
                for (int am = 0; am < 2; ++am) {
                    oacc[am][nd] = MFMA16(vf0, pa[am][0], oacc[am][nd]);
                    oacc[am][nd] = MFMA16(vf1, pa[am][1], oacc[am][nd]);
                }
            }
            #pragma unroll
            for (int am = 0; am < 2; ++am) {
                acc_sum[am] = MFMA16(onesf, pa[am][0], acc_sum[am]);
                acc_sum[am] = MFMA16(onesf, pa[am][1], acc_sum[am]);
            }
        }
        __builtin_amdgcn_s_setprio(0);

        // softmax(t): exp2 (single v_exp_f32), packed-convert into PV layout
        #pragma unroll
        for (int am = 0; am < 2; ++am) {
            float pr[4][4];
            #pragma unroll
            for (int nb = 0; nb < 4; ++nb)
                #pragma unroll
                for (int r = 0; r < 4; ++r)
                    pr[nb][r] = EXP2F(sb[am][nb][r]);
            union { bf16x8 v; u32 u[4]; } p0, p1;
            p0.u[0] = cvtpk(pr[0][0], pr[0][1]);
            p0.u[1] = cvtpk(pr[0][2], pr[0][3]);
            p0.u[2] = cvtpk(pr[2][0], pr[2][1]);
            p0.u[3] = cvtpk(pr[2][2], pr[2][3]);
            p1.u[0] = cvtpk(pr[1][0], pr[1][1]);
            p1.u[1] = cvtpk(pr[1][2], pr[1][3]);
            p1.u[2] = cvtpk(pr[3][0], pr[3][1]);
            p1.u[3] = cvtpk(pr[3][2], pr[3][3]);
            pa[am][0] = p0.v;
            pa[am][1] = p1.v;
        }
    }

    // drain: PV + sum for the last tile (slot 15&3 = 3)
    {
        u16* Vp = SM + 3 * 8192 + 4096;
        __builtin_amdgcn_s_setprio(1);
        #pragma unroll
        for (int nd = 0; nd < 4; ++nd) {
            bf16x8 vf0 = *(const bf16x8*)&Vp[nd * 1024 + lane * 8];
            bf16x8 vf1 = *(const bf16x8*)&Vp[nd * 1024 + 512 + lane * 8];
            #pragma unroll
            for (int am = 0; am < 2; ++am) {
                oacc[am][nd] = MFMA16(vf0, pa[am][0], oacc[am][nd]);
                oacc[am][nd] = MFMA16(vf1, pa[am][1], oacc[am][nd]);
            }
        }
        #pragma unroll
        for (int am = 0; am < 2; ++am) {
            acc_sum[am] = MFMA16(onesf, pa[am][0], acc_sum[am]);
            acc_sum[am] = MFMA16(onesf, pa[am][1], acc_sum[am]);
        }
        __builtin_amdgcn_s_setprio(0);
    }

    // all C rows of acc_sum are identical = total key-sum for query n_
    const float inv0 = 1.f / acc_sum[0][0];
    const float inv1 = 1.f / acc_sum[1][0];
    float inv[2] = {inv0, inv1};

    // epilogue: O^T[dk=nd*16+quad*4+r][query=n_] -> eb[query-local][dk]
    __syncthreads();   // full drain once; reuse SM
    u16* eb = SM + w * 2304;   // [32][72]
    #pragma unroll
    for (int am = 0; am < 2; ++am)
        #pragma unroll
        for (int nd = 0; nd < 4; ++nd) {
            uint2 uv;
            uv.x = cvtpk(oacc[am][nd][0] * inv[am], oacc[am][nd][1] * inv[am]);
            uv.y = cvtpk(oacc[am][nd][2] * inv[am], oacc[am][nd][3] * inv[am]);
            *(uint2*)&eb[(am * 16 + n_) * 72 + nd * 16 + quad * 4] = uv;
        }
    __syncthreads();
    #pragma unroll
    for (int t = 0; t < 4; ++t) {
        int ii = lane + t * 64;
        int row = ii >> 3, c8 = (ii & 7) * 8;
        *(bf16x8*)&obf[((size_t)b * S_ + i0 + w * 32 + row) * ND + hd * DK + c8] =
            *(const bf16x8*)&eb[row * 72 + c8];
    }
}

// ---------------------------------------------------------------------------
// Out projection: A = woT (M=c=64), B = obf (N=s=128).
// BK=64, 4 phases, double-buffered prefetch like qkv.
// C[c][s] layout -> direct coalesced stores out[b][c][s] (+bias+residual).
// ---------------------------------------------------------------------------
__global__ __launch_bounds__(256) void out_proj_mfma(
    const u16* __restrict__ obf, const u16* __restrict__ woT,
    const float* __restrict__ bo, const float* __restrict__ x,
    float* __restrict__ out)
{
    // 2 x (Bs 8192 [128 rows x 64 k] + As 4096 [64 rows x 64 k]) = 48 KB
    __shared__ __align__(16) u16 SM[24576];

    const int tid = threadIdx.x;
    const int w = tid >> 6, lane = tid & 63;
    const int n_ = lane & 15, quad = lane >> 4;
    const int c0 = blockIdx.x * 64, s0 = blockIdx.y * 128, b = blockIdx.z;

    const u16* ar  = woT + (size_t)(c0 + w * 16 + n_) * ND + quad * 8;
    const u16* br0 = obf + ((size_t)b * S_ + s0 + (2 * w + 0) * 16 + n_) * ND + quad * 8;
    const u16* br1 = obf + ((size_t)b * S_ + s0 + (2 * w + 1) * 16 + n_) * ND + quad * 8;

    f32x4 acc[2][4];
    #pragma unroll
    for (int nf = 0; nf < 2; ++nf)
        #pragma unroll
        for (int mb = 0; mb < 4; ++mb)
            #pragma unroll
            for (int r = 0; r < 4; ++r) acc[nf][mb][r] = 0.f;

    // prologue: stage phase 0 into buf 0
    {
        u16* Bs_ = SM;
        u16* As_ = SM + 8192;
        stage16(br0,      Bs_ + (4 * w + 0) * 512);
        stage16(br0 + 32, Bs_ + (4 * w + 1) * 512);
        stage16(br1,      Bs_ + (4 * w + 2) * 512);
        stage16(br1 + 32, Bs_ + (4 * w + 3) * 512);
        stage16(ar,       As_ + (2 * w + 0) * 512);
        stage16(ar + 32,  As_ + (2 * w + 1) * 512);
    }

    #pragma unroll
    for (int p = 0; p < 4; ++p) {
        u16* Bs_ = SM + (p & 1) * 12288;
        u16* As_ = Bs_ + 8192;
        if (p < 3) {
            const int pk = (p + 1) * 64;
            u16* Bn = SM + ((p + 1) & 1) * 12288;
            u16* An = Bn + 8192;
            stage16(br0 + pk,      Bn + (4 * w + 0) * 512);
            stage16(br0 + pk + 32, Bn + (4 * w + 1) * 512);
            stage16(br1 + pk,      Bn + (4 * w + 2) * 512);
            stage16(br1 + pk + 32, Bn + (4 * w + 3) * 512);
            stage16(ar  + pk,      An + (2 * w + 0) * 512);
            stage16(ar  + pk + 32, An + (2 * w + 1) * 512);
            WAITVM(6);
        } else {
            WAITVM(0);
        }
        BARRIER();
        #pragma unroll
        for (int kc = 0; kc < 2; ++kc) {
            bf16x8 bf0 = *(const bf16x8*)&Bs_[((2 * w + 0) * 2 + kc) * 512 + lane * 8];
            bf16x8 bf1 = *(const bf16x8*)&Bs_[((2 * w + 1) * 2 + kc) * 512 + lane * 8];
            #pragma unroll
            for (int mb = 0; mb < 4; ++mb) {
                bf16x8 af = *(const bf16x8*)&As_[(mb * 2 + kc) * 512 + lane * 8];
                acc[0][mb] = MFMA16(af, bf0, acc[0][mb]);
                acc[1][mb] = MFMA16(af, bf1, acc[1][mb]);
            }
        }
        if (p < 3) BARRIER();
    }

    // direct epilogue: c = c0+mb*16+quad*4+r, s = s0+w*32+nf*16+n_
    #pragma unroll
    for (int mb = 0; mb < 4; ++mb)
        #pragma unroll
        for (int r = 0; r < 4; ++r) {
            int c = c0 + mb * 16 + quad * 4 + r;
            float bias = bo[c];
            #pragma unroll
            for (int nf = 0; nf < 2; ++nf) {
                size_t idx = ((size_t)b * C_ + c) * S_ + s0 + w * 32 + nf * 16 + n_;
                out[idx] = acc[nf][mb][r] + bias + x[idx];
            }
        }
}

// ---------------------------------------------------------------------------
extern "C" void kernel_launch(void* const* d_in, const int* in_sizes, int n_in,
                              void* d_out, int out_size, void* d_ws, size_t ws_size,
                              hipStream_t stream) {
    const float* x  = (const float*)d_in[0];
    const float* wp = (const float*)d_in[1];
    const float* bp = (const float*)d_in[2];
    const float* wo = (const float*)d_in[3];
    const float* bo = (const float*)d_in[4];
    float* out = (float*)d_out;

    const size_t QKV_E = (size_t)B_ * NH * S_ * DK;   // 4 Mi
    u16* q   = (u16*)d_ws;
    u16* kk  = q   + QKV_E;
    u16* vtp = kk  + QKV_E;
    u16* obf = vtp + QKV_E;                            // B*S*ND
    u16* xt  = obf + (size_t)B_ * S_ * ND;             // B*S*C
    u16* wpT = xt  + (size_t)B_ * S_ * C_;             // P3*C
    u16* woT = wpT + (size_t)P3 * C_;                  // C*ND

    transpose_all<<<dim3(16, 4, 18),             256, 0, stream>>>(x, xt, wp, wpT, wo, woT);
    qkv_mfma     <<<dim3(P3 / 64, S_ / 128, B_), 256, 0, stream>>>(xt, wpT, bp, q, kk, vtp);
    attn_mfma    <<<dim3(512, 1, 1),             256, 0, stream>>>(q, kk, vtp, obf);
    out_proj_mfma<<<dim3(C_ / 64, S_ / 128, B_), 256, 0, stream>>>(obf, woT, bo, x, out);
}

// Round 5
// 121.645 us; speedup vs baseline: 1.1837x; 1.0586x over previous
//
#include <hip/hip_runtime.h>
#include <math.h>

#define B_  16
#define C_  256
#define S_  1024
#define NH  4
#define DK  64
#define P3  768   // 3*NH*DK
#define ND  256   // NH*DK

typedef unsigned short u16;
typedef unsigned int   u32;
typedef float  f32x4  __attribute__((ext_vector_type(4)));
typedef short  bf16x8 __attribute__((ext_vector_type(8)));

#define MFMA16(a, b, c) __builtin_amdgcn_mfma_f32_16x16x32_bf16(a, b, c, 0, 0, 0)

// fold softmax scale*log2(e) into q at projection time
#define QSCALE 0.1803368801111137f   // 0.125 * 1.44269504

// counted waitcnt + raw barrier (no vmcnt(0) drain — the __syncthreads killer)
#define WAITVM(N) asm volatile("s_waitcnt vmcnt(" #N ")" ::: "memory")
#define BARRIER() asm volatile("s_barrier" ::: "memory")

#if __has_builtin(__builtin_amdgcn_exp2f)
#define EXP2F(x) __builtin_amdgcn_exp2f(x)
#else
#define EXP2F(x) exp2f(x)
#endif

__device__ __forceinline__ u16 f2bf(float f) {
    union { float f; u32 u; } x; x.f = f;
    u32 r = x.u + 0x7fffu + ((x.u >> 16) & 1u);   // RNE
    return (u16)(r >> 16);
}

// packed f32 pair -> 2x bf16 in one VALU op (RNE)
__device__ __forceinline__ u32 cvtpk(float lo, float hi) {
    u32 r;
    asm("v_cvt_pk_bf16_f32 %0, %1, %2" : "=v"(r) : "v"(lo), "v"(hi));
    return r;
}

// async global->LDS, 16B per lane; LDS dest is wave-uniform base + lane*16
__device__ __forceinline__ void stage16(const u16* g, u16* l) {
    __builtin_amdgcn_global_load_lds(
        (const __attribute__((address_space(1))) void*)g,
        (__attribute__((address_space(3))) void*)l, 16, 0, 0);
}

// ---------------------------------------------------------------------------
// Weight transposes only (x-transpose now fused into qkv):
//   z=0: w_proj [256][768] -> wpT [768][256]
//   z=1: w_out  [256][256] -> woT [256][256]
// ---------------------------------------------------------------------------
__global__ __launch_bounds__(256) void transpose_w(
    const float* __restrict__ wp, u16* __restrict__ wpT,
    const float* __restrict__ wo, u16* __restrict__ woT)
{
    const int z = blockIdx.z;
    const int Cc = z ? 256 : 768;
    if ((int)blockIdx.x * 64 >= Cc) return;
    const float* src = z ? wo : wp;
    u16* dst = z ? woT : wpT;
    const int R = 256;

    __shared__ float T[64][65];
    const int tid = threadIdx.x;
    const int c0 = blockIdx.x * 64, r0 = blockIdx.y * 64;

    const int l64 = tid & 63, rr0 = tid >> 6;
    #pragma unroll
    for (int t = 0; t < 16; ++t) {
        int rr = rr0 + t * 4;
        T[rr][l64] = src[(size_t)(r0 + rr) * Cc + c0 + l64];
    }
    __syncthreads();
    const int rp = tid & 31;
    const int cb = tid >> 5;
    #pragma unroll
    for (int t = 0; t < 8; ++t) {
        int c = cb + t * 8;
        u32 lo = f2bf(T[2 * rp][c]);
        u32 hi = f2bf(T[2 * rp + 1][c]);
        *(u32*)&dst[(size_t)(c0 + c) * R + r0 + 2 * rp] = lo | (hi << 16);
    }
}

// ---------------------------------------------------------------------------
// FUSED QKV projection: block = one head's full panel, 128(M=s) x 192(N=n),
// K=256, BK=64, 4 phases, double-buffered (80 KB LDS = exactly 2 blocks/CU,
// grid 512 = all resident). A-operand staged DIRECTLY from fp32 x (coalesced
// float4 along s, issued pre-MFMA), cvt_pk -> bf16, conflict-free
// ds_write_b128 into a row-rotated chunk layout; frag reads use the same
// rotation. Eliminates the separate x-transpose kernel entirely.
// N=192 => x re-read only 4x (vs 12x); XCD-chunked grid => 2 MB x-set per
// XCD L2. Epilogue writes q (QSCALE folded), k, v-transposed in one pass.
// ---------------------------------------------------------------------------
__global__ __launch_bounds__(256, 2) void qkv_fused(
    const float* __restrict__ x, const u16* __restrict__ wpT,
    const float* __restrict__ bp, u16* __restrict__ qo,
    u16* __restrict__ ko, u16* __restrict__ vo)
{
    // 2 x (As 8192 u16 [128s x 64k rotated] + Bs 12288 u16 [192n x 64k]) = 80 KB
    __shared__ __align__(16) u16 SM[40960];

    const int tid = threadIdx.x;
    const int w = tid >> 6, lane = tid & 63;
    const int n_ = lane & 15, quad = lane >> 4;

    // XCD-chunked 1D grid: 4 head-blocks of one (b,s0) group adjacent per XCD
    const int id  = blockIdx.x;
    const int nid = (id & 7) * 64 + (id >> 3);
    const int hd  = nid & 3;
    const int g   = nid >> 2;
    const int s0  = (g & 7) * 128;
    const int b   = g >> 3;
    const int bh  = b * NH + hd;

    // ---- A-staging role: thread = (kq8 = 8 k-columns, row4 = 4 s-rows) ----
    const int kq8  = tid >> 5;    // 0..7 -> k = kq8*8..+7 within the 64-k phase
    const int row4 = tid & 31;    // rows row4*4..+3
    const float* xb = x + ((size_t)b * C_ + kq8 * 8) * S_ + s0 + row4 * 4;

    int awaddr[4];
    {
        const int kc = kq8 >> 2, quadk = kq8 & 3;
        #pragma unroll
        for (int j = 0; j < 4; ++j) {
            int row = row4 * 4 + j;
            awaddr[j] = ((row >> 4) * 2 + kc) * 512 + quadk * 128 +
                        ((((row & 15) + (row >> 4)) & 15) * 8);
        }
    }

    // ---- B staging: wave w stages n-rowgroups w*3..w*3+2, kc 0..1 ----
    const u16* brp[3];
    #pragma unroll
    for (int i = 0; i < 3; ++i)
        brp[i] = wpT + (size_t)(hd * 192 + (w * 3 + i) * 16 + n_) * C_ + quad * 8;

    f32x4 acc[2][12];
    #pragma unroll
    for (int am = 0; am < 2; ++am)
        #pragma unroll
        for (int nf = 0; nf < 12; ++nf)
            #pragma unroll
            for (int r = 0; r < 4; ++r) acc[am][nf][r] = 0.f;

    float4 av[8];

    // ---- prologue: phase 0 into buf 0 ----
    #pragma unroll
    for (int ci = 0; ci < 8; ++ci)
        av[ci] = *(const float4*)(xb + (size_t)ci * S_);
    {
        u16* Bs0 = SM + 8192;
        #pragma unroll
        for (int i = 0; i < 3; ++i) {
            stage16(brp[i],      Bs0 + ((w * 3 + i) * 2 + 0) * 512);
            stage16(brp[i] + 32, Bs0 + ((w * 3 + i) * 2 + 1) * 512);
        }
    }
    #pragma unroll
    for (int j = 0; j < 4; ++j) {
        union { bf16x8 v; u32 u[4]; } pk;
        pk.u[0] = cvtpk(av[0][j], av[1][j]);
        pk.u[1] = cvtpk(av[2][j], av[3][j]);
        pk.u[2] = cvtpk(av[4][j], av[5][j]);
        pk.u[3] = cvtpk(av[6][j], av[7][j]);
        *(bf16x8*)&SM[awaddr[j]] = pk.v;
    }
    __syncthreads();

    // ---- main loop: 4 K-phases ----
    #pragma unroll
    for (int p = 0; p < 4; ++p) {
        u16* As_ = SM + (p & 1) * 20480;
        u16* Bs_ = As_ + 8192;
        u16* An  = SM + ((p + 1) & 1) * 20480;
        u16* Bn  = An + 8192;

        if (p < 3) {
            // issue next-phase A loads (consumed after MFMA) and B stages
            #pragma unroll
            for (int ci = 0; ci < 8; ++ci)
                av[ci] = *(const float4*)(xb + ((size_t)(p + 1) * 64 + ci) * S_);
            #pragma unroll
            for (int i = 0; i < 3; ++i) {
                stage16(brp[i] + (p + 1) * 64,      Bn + ((w * 3 + i) * 2 + 0) * 512);
                stage16(brp[i] + (p + 1) * 64 + 32, Bn + ((w * 3 + i) * 2 + 1) * 512);
            }
        }

        #pragma unroll
        for (int kc = 0; kc < 2; ++kc) {
            bf16x8 af0 = *(const bf16x8*)&As_[((2 * w + 0) * 2 + kc) * 512 +
                                              quad * 128 + (((n_ + 2 * w + 0) & 15) * 8)];
            bf16x8 af1 = *(const bf16x8*)&As_[((2 * w + 1) * 2 + kc) * 512 +
                                              quad * 128 + (((n_ + 2 * w + 1) & 15) * 8)];
            #pragma unroll
            for (int nf = 0; nf < 12; ++nf) {
                bf16x8 bf = *(const bf16x8*)&Bs_[(nf * 2 + kc) * 512 + lane * 8];
                acc[0][nf] = MFMA16(af0, bf, acc[0][nf]);
                acc[1][nf] = MFMA16(af1, bf, acc[1][nf]);
            }
        }

        if (p < 3) {
            #pragma unroll
            for (int j = 0; j < 4; ++j) {
                union { bf16x8 v; u32 u[4]; } pk;
                pk.u[0] = cvtpk(av[0][j], av[1][j]);
                pk.u[1] = cvtpk(av[2][j], av[3][j]);
                pk.u[2] = cvtpk(av[4][j], av[5][j]);
                pk.u[3] = cvtpk(av[6][j], av[7][j]);
                *(bf16x8*)&An[awaddr[j]] = pk.v;
            }
        }
        __syncthreads();
    }

    // ---- epilogue: q (scaled), k, v-transposed via LDS ----
    float bias[12];
    #pragma unroll
    for (int nf = 0; nf < 12; ++nf) bias[nf] = bp[hd * 192 + nf * 16 + n_];

    u16* Cq = SM;              // [128][72]
    u16* Ck = SM + 9216;       // [128][72]
    u16* Cv = SM + 18432;      // [64][136]

    #pragma unroll
    for (int am = 0; am < 2; ++am) {
        int row0 = w * 32 + am * 16 + quad * 4;
        #pragma unroll
        for (int nf = 0; nf < 4; ++nf)
            #pragma unroll
            for (int r = 0; r < 4; ++r)
                Cq[(row0 + r) * 72 + nf * 16 + n_] =
                    f2bf((acc[am][nf][r] + bias[nf]) * QSCALE);
        #pragma unroll
        for (int nf = 4; nf < 8; ++nf)
            #pragma unroll
            for (int r = 0; r < 4; ++r)
                Ck[(row0 + r) * 72 + (nf - 4) * 16 + n_] =
                    f2bf(acc[am][nf][r] + bias[nf]);
        int colb = w * 32 + am * 16 + quad * 4;
        #pragma unroll
        for (int nf = 8; nf < 12; ++nf)
            #pragma unroll
            for (int r = 0; r < 4; ++r)
                Cv[((nf - 8) * 16 + n_) * 136 + colb + r] =
                    f2bf(acc[am][nf][r] + bias[nf]);
    }
    __syncthreads();

    #pragma unroll
    for (int t = 0; t < 4; ++t) {
        int ii = tid + t * 256;
        int row = ii >> 3, c8 = (ii & 7) * 8;
        *(bf16x8*)&qo[((size_t)bh * S_ + s0 + row) * DK + c8] =
            *(const bf16x8*)&Cq[row * 72 + c8];
        *(bf16x8*)&ko[((size_t)bh * S_ + s0 + row) * DK + c8] =
            *(const bf16x8*)&Ck[row * 72 + c8];
        int vrow = ii >> 4, vc8 = (ii & 15) * 8;
        *(bf16x8*)&vo[((size_t)bh * DK + vrow) * S_ + s0 + vc8] =
            *(const bf16x8*)&Cv[vrow * 136 + vc8];
    }
}

// ---------------------------------------------------------------------------
// Flash attention: block = 128 q (4 waves x 32 q), 64-key tiles, no-max
// softmax. S computed TRANSPOSED (A=K with kappa-permuted rows, B=Q) so the
// P^T C-layout -> PV B-operand transform is a pure register repack.
// T15 2-tile pipeline: iter t = QK(t) MFMA -> PV(t-1) MFMA (independent of
// softmax(t), fills matrix pipe while VALU runs) -> softmax(t) -> pa.
// Row-sum via ones-MFMA. Ring-4 LDS, staging after barrier, vmcnt(4).
// ---------------------------------------------------------------------------
__global__ __launch_bounds__(256) void attn_mfma(
    const u16* __restrict__ q, const u16* __restrict__ k,
    const u16* __restrict__ vt, u16* __restrict__ obf)
{
    // ring of 4 x (Ks 4096 u16 + Vs 4096 u16) = 64 KB; epilogue reuses SM
    __shared__ __align__(16) u16 SM[32768];

    const int tid = threadIdx.x;
    const int w = tid >> 6, lane = tid & 63;
    const int n_ = lane & 15, quad = lane >> 4;

    // XCD swizzle: 512 blocks, 8 XCDs, 64-block chunks (8 complete heads/XCD)
    const int id  = blockIdx.x;
    const int nid = (id & 7) * 64 + (id >> 3);
    const int i0  = (nid & 7) * 128;
    const int bh  = nid >> 3;
    const int hd  = bh & 3;
    const int b   = bh >> 2;

    // Q fragments (B-operand; scale pre-folded): query = i0 + w*32 + am*16 + n_
    bf16x8 qf[2][2];
    #pragma unroll
    for (int am = 0; am < 2; ++am) {
        const u16* qrow = q + ((size_t)bh * S_ + i0 + w * 32 + am * 16 + n_) * DK;
        qf[am][0] = *(const bf16x8*)&qrow[quad * 8];
        qf[am][1] = *(const bf16x8*)&qrow[32 + quad * 8];
    }

    // all-ones bf16 A-fragment for the row-sum MFMA (layout-independent)
    union { bf16x8 v; u32 u[4]; } ones_;
    #pragma unroll
    for (int i = 0; i < 4; ++i) ones_.u[i] = 0x3F803F80u;
    const bf16x8 onesf = ones_.v;

    // K staging with kappa row permutation (staging wave w = MFMA block nb)
    const int kappa = 32 * (w & 1) + 8 * (n_ >> 2) + 4 * (w >> 1) + (n_ & 3);
    const u16* kbase = k  + ((size_t)bh * S_ + kappa) * DK + quad * 8;
    const u16* vbase = vt + ((size_t)bh * DK + w * 16 + n_) * S_ + quad * 8;

    f32x4 oacc[2][4];
    f32x4 acc_sum[2];
    #pragma unroll
    for (int am = 0; am < 2; ++am) {
        #pragma unroll
        for (int nd = 0; nd < 4; ++nd)
            #pragma unroll
            for (int r = 0; r < 4; ++r) oacc[am][nd][r] = 0.f;
        #pragma unroll
        for (int r = 0; r < 4; ++r) acc_sum[am][r] = 0.f;
    }

    // prologue: tiles 0 and 1 into slots 0 and 1 (8 loads/wave)
    stage16(kbase,                SM + w * 1024);
    stage16(kbase + 32,           SM + w * 1024 + 512);
    stage16(vbase,                SM + 4096 + w * 1024);
    stage16(vbase + 32,           SM + 4096 + w * 1024 + 512);
    stage16(kbase + 64 * DK,      SM + 8192 + w * 1024);
    stage16(kbase + 64 * DK + 32, SM + 8192 + w * 1024 + 512);
    stage16(vbase + 64,           SM + 8192 + 4096 + w * 1024);
    stage16(vbase + 64 + 32,      SM + 8192 + 4096 + w * 1024 + 512);

    bf16x8 pa[2][2];   // packed P of the PREVIOUS tile (valid for t >= 1)

    for (int t = 0; t < 16; ++t) {
        u16* Ks = SM + (t & 3) * 8192;
        u16* Vp = SM + ((t + 3) & 3) * 8192 + 4096;   // Vs of tile t-1
        if (t < 15) WAITVM(4); else WAITVM(0);
        BARRIER();
        if (t < 14) {
            const size_t jn = (size_t)(t + 2) * 64;
            u16* Kn = SM + ((t + 2) & 3) * 8192;
            u16* Vn = Kn + 4096;
            stage16(kbase + jn * DK,      Kn + w * 1024);
            stage16(kbase + jn * DK + 32, Kn + w * 1024 + 512);
            stage16(vbase + jn,           Vn + w * 1024);
            stage16(vbase + jn + 32,      Vn + w * 1024 + 512);
        }

        // S^T(t) = K Q^T : C rows = permuted keys, cols = queries (n_)
        f32x4 sb[2][4];
        __builtin_amdgcn_s_setprio(1);
        #pragma unroll
        for (int nb = 0; nb < 4; ++nb) {
            bf16x8 kf0 = *(const bf16x8*)&Ks[nb * 1024 + lane * 8];
            bf16x8 kf1 = *(const bf16x8*)&Ks[nb * 1024 + 512 + lane * 8];
            #pragma unroll
            for (int am = 0; am < 2; ++am) {
                f32x4 a; a[0] = a[1] = a[2] = a[3] = 0.f;
                a = MFMA16(kf0, qf[am][0], a);
                a = MFMA16(kf1, qf[am][1], a);
                sb[am][nb] = a;
            }
        }

        // PV(t-1): independent of sb(t) -> overlaps softmax below.
        if (t > 0) {
            #pragma unroll
            for (int nd = 0; nd < 4; ++nd) {
                bf16x8 vf0 = *(const bf16x8*)&Vp[nd * 1024 + lane * 8];
                bf16x8 vf1 = *(const bf16x8*)&Vp[nd * 1024 + 512 + lane * 8];
                #pragma unroll
                for (int am = 0; am < 2; ++am) {
                    oacc[am][nd] = MFMA16(vf0, pa[am][0], oacc[am][nd]);
                    oacc[am][nd] = MFMA16(vf1, pa[am][1], oacc[am][nd]);
                }
            }
            #pragma unroll
            for (int am = 0; am < 2; ++am) {
                acc_sum[am] = MFMA16(onesf, pa[am][0], acc_sum[am]);
                acc_sum[am] = MFMA16(onesf, pa[am][1], acc_sum[am]);
            }
        }
        __builtin_amdgcn_s_setprio(0);

        // softmax(t): exp2 (single v_exp_f32), packed-convert into PV layout
        #pragma unroll
        for (int am = 0; am < 2; ++am) {
            float pr[4][4];
            #pragma unroll
            for (int nb = 0; nb < 4; ++nb)
                #pragma unroll
                for (int r = 0; r < 4; ++r)
                    pr[nb][r] = EXP2F(sb[am][nb][r]);
            union { bf16x8 v; u32 u[4]; } p0, p1;
            p0.u[0] = cvtpk(pr[0][0], pr[0][1]);
            p0.u[1] = cvtpk(pr[0][2], pr[0][3]);
            p0.u[2] = cvtpk(pr[2][0], pr[2][1]);
            p0.u[3] = cvtpk(pr[2][2], pr[2][3]);
            p1.u[0] = cvtpk(pr[1][0], pr[1][1]);
            p1.u[1] = cvtpk(pr[1][2], pr[1][3]);
            p1.u[2] = cvtpk(pr[3][0], pr[3][1]);
            p1.u[3] = cvtpk(pr[3][2], pr[3][3]);
            pa[am][0] = p0.v;
            pa[am][1] = p1.v;
        }
    }

    // drain: PV + sum for the last tile (slot 15&3 = 3)
    {
        u16* Vp = SM + 3 * 8192 + 4096;
        __builtin_amdgcn_s_setprio(1);
        #pragma unroll
        for (int nd = 0; nd < 4; ++nd) {
            bf16x8 vf0 = *(const bf16x8*)&Vp[nd * 1024 + lane * 8];
            bf16x8 vf1 = *(const bf16x8*)&Vp[nd * 1024 + 512 + lane * 8];
            #pragma unroll
            for (int am = 0; am < 2; ++am) {
                oacc[am][nd] = MFMA16(vf0, pa[am][0], oacc[am][nd]);
                oacc[am][nd] = MFMA16(vf1, pa[am][1], oacc[am][nd]);
            }
        }
        #pragma unroll
        for (int am = 0; am < 2; ++am) {
            acc_sum[am] = MFMA16(onesf, pa[am][0], acc_sum[am]);
            acc_sum[am] = MFMA16(onesf, pa[am][1], acc_sum[am]);
        }
        __builtin_amdgcn_s_setprio(0);
    }

    const float inv0 = 1.f / acc_sum[0][0];
    const float inv1 = 1.f / acc_sum[1][0];
    float inv[2] = {inv0, inv1};

    // epilogue: O^T[dk=nd*16+quad*4+r][query=n_] -> eb[query-local][dk]
    __syncthreads();   // full drain once; reuse SM
    u16* eb = SM + w * 2304;   // [32][72]
    #pragma unroll
    for (int am = 0; am < 2; ++am)
        #pragma unroll
        for (int nd = 0; nd < 4; ++nd) {
            uint2 uv;
            uv.x = cvtpk(oacc[am][nd][0] * inv[am], oacc[am][nd][1] * inv[am]);
            uv.y = cvtpk(oacc[am][nd][2] * inv[am], oacc[am][nd][3] * inv[am]);
            *(uint2*)&eb[(am * 16 + n_) * 72 + nd * 16 + quad * 4] = uv;
        }
    __syncthreads();
    #pragma unroll
    for (int t = 0; t < 4; ++t) {
        int ii = lane + t * 64;
        int row = ii >> 3, c8 = (ii & 7) * 8;
        *(bf16x8*)&obf[((size_t)b * S_ + i0 + w * 32 + row) * ND + hd * DK + c8] =
            *(const bf16x8*)&eb[row * 72 + c8];
    }
}

// ---------------------------------------------------------------------------
// Out projection: A = woT (M=c=64), B = obf (N=s=128).
// BK=64, 4 phases, double-buffered prefetch.
// C[c][s] layout -> direct coalesced stores out[b][c][s] (+bias+residual).
// ---------------------------------------------------------------------------
__global__ __launch_bounds__(256) void out_proj_mfma(
    const u16* __restrict__ obf, const u16* __restrict__ woT,
    const float* __restrict__ bo, const float* __restrict__ x,
    float* __restrict__ out)
{
    // 2 x (Bs 8192 [128 rows x 64 k] + As 4096 [64 rows x 64 k]) = 48 KB
    __shared__ __align__(16) u16 SM[24576];

    const int tid = threadIdx.x;
    const int w = tid >> 6, lane = tid & 63;
    const int n_ = lane & 15, quad = lane >> 4;
    const int c0 = blockIdx.x * 64, s0 = blockIdx.y * 128, b = blockIdx.z;

    const u16* ar  = woT + (size_t)(c0 + w * 16 + n_) * ND + quad * 8;
    const u16* br0 = obf + ((size_t)b * S_ + s0 + (2 * w + 0) * 16 + n_) * ND + quad * 8;
    const u16* br1 = obf + ((size_t)b * S_ + s0 + (2 * w + 1) * 16 + n_) * ND + quad * 8;

    f32x4 acc[2][4];
    #pragma unroll
    for (int nf = 0; nf < 2; ++nf)
        #pragma unroll
        for (int mb = 0; mb < 4; ++mb)
            #pragma unroll
            for (int r = 0; r < 4; ++r) acc[nf][mb][r] = 0.f;

    // prologue: stage phase 0 into buf 0
    {
        u16* Bs_ = SM;
        u16* As_ = SM + 8192;
        stage16(br0,      Bs_ + (4 * w + 0) * 512);
        stage16(br0 + 32, Bs_ + (4 * w + 1) * 512);
        stage16(br1,      Bs_ + (4 * w + 2) * 512);
        stage16(br1 + 32, Bs_ + (4 * w + 3) * 512);
        stage16(ar,       As_ + (2 * w + 0) * 512);
        stage16(ar + 32,  As_ + (2 * w + 1) * 512);
    }

    #pragma unroll
    for (int p = 0; p < 4; ++p) {
        u16* Bs_ = SM + (p & 1) * 12288;
        u16* As_ = Bs_ + 8192;
        if (p < 3) {
            const int pk = (p + 1) * 64;
            u16* Bn = SM + ((p + 1) & 1) * 12288;
            u16* An = Bn + 8192;
            stage16(br0 + pk,      Bn + (4 * w + 0) * 512);
            stage16(br0 + pk + 32, Bn + (4 * w + 1) * 512);
            stage16(br1 + pk,      Bn + (4 * w + 2) * 512);
            stage16(br1 + pk + 32, Bn + (4 * w + 3) * 512);
            stage16(ar  + pk,      An + (2 * w + 0) * 512);
            stage16(ar  + pk + 32, An + (2 * w + 1) * 512);
            WAITVM(6);
        } else {
            WAITVM(0);
        }
        BARRIER();
        #pragma unroll
        for (int kc = 0; kc < 2; ++kc) {
            bf16x8 bf0 = *(const bf16x8*)&Bs_[((2 * w + 0) * 2 + kc) * 512 + lane * 8];
            bf16x8 bf1 = *(const bf16x8*)&Bs_[((2 * w + 1) * 2 + kc) * 512 + lane * 8];
            #pragma unroll
            for (int mb = 0; mb < 4; ++mb) {
                bf16x8 af = *(const bf16x8*)&As_[(mb * 2 + kc) * 512 + lane * 8];
                acc[0][mb] = MFMA16(af, bf0, acc[0][mb]);
                acc[1][mb] = MFMA16(af, bf1, acc[1][mb]);
            }
        }
        if (p < 3) BARRIER();
    }

    // direct epilogue: c = c0+mb*16+quad*4+r, s = s0+w*32+nf*16+n_
    #pragma unroll
    for (int mb = 0; mb < 4; ++mb)
        #pragma unroll
        for (int r = 0; r < 4; ++r) {
            int c = c0 + mb * 16 + quad * 4 + r;
            float bias = bo[c];
            #pragma unroll
            for (int nf = 0; nf < 2; ++nf) {
                size_t idx = ((size_t)b * C_ + c) * S_ + s0 + w * 32 + nf * 16 + n_;
                out[idx] = acc[nf][mb][r] + bias + x[idx];
            }
        }
}

// ---------------------------------------------------------------------------
extern "C" void kernel_launch(void* const* d_in, const int* in_sizes, int n_in,
                              void* d_out, int out_size, void* d_ws, size_t ws_size,
                              hipStream_t stream) {
    const float* x  = (const float*)d_in[0];
    const float* wp = (const float*)d_in[1];
    const float* bp = (const float*)d_in[2];
    const float* wo = (const float*)d_in[3];
    const float* bo = (const float*)d_in[4];
    float* out = (float*)d_out;

    const size_t QKV_E = (size_t)B_ * NH * S_ * DK;   // 4 Mi
    u16* q   = (u16*)d_ws;
    u16* kk  = q   + QKV_E;
    u16* vtp = kk  + QKV_E;
    u16* obf = vtp + QKV_E;                            // B*S*ND
    u16* wpT = obf + (size_t)B_ * S_ * ND;             // P3*C
    u16* woT = wpT + (size_t)P3 * C_;                  // C*ND

    transpose_w  <<<dim3(12, 4, 2),              256, 0, stream>>>(wp, wpT, wo, woT);
    qkv_fused    <<<dim3(512, 1, 1),             256, 0, stream>>>(x, wpT, bp, q, kk, vtp);
    attn_mfma    <<<dim3(512, 1, 1),             256, 0, stream>>>(q, kk, vtp, obf);
    out_proj_mfma<<<dim3(C_ / 64, S_ / 128, B_), 256, 0, stream>>>(obf, woT, bo, x, out);
}